// Round 5
// baseline (722.837 us; speedup 1.0000x reference)
//
#include <hip/hip_runtime.h>
#include <hip/hip_bf16.h>

#define NN 50000
#define EE 1600000
#define DH 128
#define DOUT 64
#define NEG 0.2f
#define NBK 256            // bucket array size (used: (NN+255)>>8 = 196)
#define CHUNK 4096         // edges per scatter block

// ---------------- CSR build (bucketed) ----------------

__global__ __launch_bounds__(256) void k_hist(const int* __restrict__ dst,
                                              int* __restrict__ deg,
                                              int* __restrict__ bucket_hist) {
    __shared__ int lh[NBK];
    lh[threadIdx.x] = 0;
    __syncthreads();
    const int e0 = blockIdx.x * CHUNK;
    #pragma unroll
    for (int k = 0; k < CHUNK / 256; k++) {
        int e = e0 + k * 256 + threadIdx.x;
        if (e < EE) {
            int d = dst[e];
            atomicAdd(&deg[d], 1);
            atomicAdd(&lh[((unsigned)d) >> 8], 1);
        }
    }
    __syncthreads();
    int c = lh[threadIdx.x];
    if (c) atomicAdd(&bucket_hist[threadIdx.x], c);
}

__global__ __launch_bounds__(256) void k_scan_bucket(const int* __restrict__ bucket_hist,
                                                     int* __restrict__ bucket_cursor) {
    __shared__ int tmp[NBK];
    int t = threadIdx.x;
    int v = bucket_hist[t];
    tmp[t] = v;
    __syncthreads();
    #pragma unroll
    for (int off = 1; off < NBK; off <<= 1) {
        int tt = (t >= off) ? tmp[t - off] : 0;
        __syncthreads();
        tmp[t] += tt;
        __syncthreads();
    }
    bucket_cursor[t] = tmp[t] - v;
}

__global__ __launch_bounds__(256) void k_scatter(const int* __restrict__ src,
                                                 const int* __restrict__ dst,
                                                 int* __restrict__ bucket_cursor,
                                                 uint2* __restrict__ pairs) {
    __shared__ int lh[NBK];
    __shared__ int lbase[NBK];
    lh[threadIdx.x] = 0;
    __syncthreads();
    const int e0 = blockIdx.x * CHUNK;
    int dl[CHUNK / 256];
    #pragma unroll
    for (int k = 0; k < CHUNK / 256; k++) {
        int e = e0 + k * 256 + threadIdx.x;
        dl[k] = (e < EE) ? dst[e] : -1;
        if (dl[k] >= 0) atomicAdd(&lh[((unsigned)dl[k]) >> 8], 1);
    }
    __syncthreads();
    int c = lh[threadIdx.x];
    lbase[threadIdx.x] = c ? atomicAdd(&bucket_cursor[threadIdx.x], c) : 0;
    __syncthreads();
    lh[threadIdx.x] = 0;   // reuse as local running cursor
    __syncthreads();
    #pragma unroll
    for (int k = 0; k < CHUNK / 256; k++) {
        int e = e0 + k * 256 + threadIdx.x;
        if (dl[k] >= 0) {
            int b = ((unsigned)dl[k]) >> 8;
            int loc = atomicAdd(&lh[b], 1);
            pairs[lbase[b] + loc] = make_uint2((unsigned)src[e], (unsigned)dl[k]);
        }
    }
}

__global__ __launch_bounds__(256) void k_scan_block(const int* __restrict__ deg,
                                                    int* __restrict__ out,
                                                    int* __restrict__ bsums, int n) {
    __shared__ int tmp[256];
    int i = blockIdx.x * 256 + threadIdx.x;
    int v = (i < n) ? ((deg[i] + 7) & ~7) : 0;
    tmp[threadIdx.x] = v;
    __syncthreads();
    #pragma unroll
    for (int off = 1; off < 256; off <<= 1) {
        int t = (threadIdx.x >= off) ? tmp[threadIdx.x - off] : 0;
        __syncthreads();
        tmp[threadIdx.x] += t;
        __syncthreads();
    }
    if (i < n) out[i] = tmp[threadIdx.x] - v;
    if (threadIdx.x == 255) bsums[blockIdx.x] = tmp[255];
}

__global__ __launch_bounds__(256) void k_scan_aux(int* __restrict__ bsums, int nb) {
    __shared__ int tmp[256];
    int t = threadIdx.x;
    int v = (t < nb) ? bsums[t] : 0;
    tmp[t] = v;
    __syncthreads();
    #pragma unroll
    for (int off = 1; off < 256; off <<= 1) {
        int tt = (t >= off) ? tmp[t - off] : 0;
        __syncthreads();
        tmp[t] += tt;
        __syncthreads();
    }
    if (t < nb) bsums[t] = tmp[t] - v;
}

__global__ __launch_bounds__(256) void k_scan_add(int* __restrict__ out,
                                                  const int* __restrict__ bsums, int n) {
    int i = blockIdx.x * 256 + threadIdx.x;
    if (i < n) out[i] += bsums[blockIdx.x];
}

// final fill: pairs (bucket-ordered) -> csr at padded row positions.
// stores PRE-MULTIPLIED byte offset (src * 256) of the bf16 feature row.
__global__ __launch_bounds__(256) void k_fill2(const uint2* __restrict__ pairs,
                                               const int* __restrict__ prow,
                                               int* __restrict__ cursor,
                                               int* __restrict__ csr_off) {
    int e = blockIdx.x * 256 + threadIdx.x;
    if (e < EE) {
        uint2 pr = pairs[e];
        int d = (int)pr.y;
        int pos = prow[d] + atomicAdd(&cursor[d], 1);
        csr_off[pos] = (int)(pr.x << 8);
    }
}

// pad slots -> offset 0 (node 0's row; logit killed in gat kernel)
__global__ __launch_bounds__(256) void k_pad(const int* __restrict__ deg,
                                             const int* __restrict__ prow,
                                             int* __restrict__ csr_off) {
    int n = blockIdx.x * 256 + threadIdx.x;
    if (n < NN) {
        int d = deg[n];
        int p = prow[n] + d;
        int e = prow[n] + ((d + 7) & ~7);
        for (; p < e; ++p) csr_off[p] = 0;
    }
}

// ---------------- helpers ----------------

static __device__ __forceinline__ unsigned short f2bf(float f) {
    unsigned int u = __float_as_uint(f);
    unsigned int r = (u + 0x7fffu + ((u >> 16) & 1u)) >> 16;  // RNE
    return (unsigned short)r;
}

// ---------------- GEMM: C[n,m] = sum_k X[n,k]*W[m,k] + b[m], K=128 ----------------

template <int BN>
__global__ __launch_bounds__(256) void k_gemm(const float* __restrict__ X,
                                              const float* __restrict__ W,
                                              const float* __restrict__ bias,
                                              float* __restrict__ C, int nrows) {
    constexpr int BM = 128, BK = 32, K = 128;
    constexpr int TM = 8;
    constexpr int TN = BN / 16;
    __shared__ float Xs[BK][BM + 4];
    __shared__ float Ws[BK][BN + 4];

    const int tid = threadIdx.x;
    const int tx = tid & 15;
    const int ty = tid >> 4;
    const int row0 = blockIdx.x * BM;

    float acc[TM][TN];
    #pragma unroll
    for (int i = 0; i < TM; i++)
        #pragma unroll
        for (int j = 0; j < TN; j++) acc[i][j] = 0.f;

    const int r = tid >> 3;
    const int kq = tid & 7;

    for (int k0 = 0; k0 < K; k0 += BK) {
        #pragma unroll
        for (int rr = 0; rr < BM; rr += 32) {
            int gr = row0 + r + rr;
            float4 v = make_float4(0.f, 0.f, 0.f, 0.f);
            if (gr < nrows) v = *(const float4*)&X[(size_t)gr * K + k0 + kq * 4];
            Xs[kq * 4 + 0][r + rr] = v.x;
            Xs[kq * 4 + 1][r + rr] = v.y;
            Xs[kq * 4 + 2][r + rr] = v.z;
            Xs[kq * 4 + 3][r + rr] = v.w;
        }
        #pragma unroll
        for (int rr = 0; rr < BN; rr += 32) {
            int m = r + rr;
            float4 v = *(const float4*)&W[(size_t)m * K + k0 + kq * 4];
            Ws[kq * 4 + 0][m] = v.x;
            Ws[kq * 4 + 1][m] = v.y;
            Ws[kq * 4 + 2][m] = v.z;
            Ws[kq * 4 + 3][m] = v.w;
        }
        __syncthreads();
        #pragma unroll
        for (int k = 0; k < BK; ++k) {
            float xv[TM], wv[TN];
            #pragma unroll
            for (int i = 0; i < TM; i += 4)
                *(float4*)&xv[i] = *(const float4*)&Xs[k][ty * TM + i];
            #pragma unroll
            for (int j = 0; j < TN; j += 4)
                *(float4*)&wv[j] = *(const float4*)&Ws[k][tx * TN + j];
            #pragma unroll
            for (int i = 0; i < TM; i++)
                #pragma unroll
                for (int j = 0; j < TN; j++) acc[i][j] += xv[i] * wv[j];
        }
        __syncthreads();
    }

    #pragma unroll
    for (int i = 0; i < TM; i++) {
        int gr = row0 + ty * TM + i;
        if (gr < nrows) {
            #pragma unroll
            for (int j = 0; j < TN; j += 4) {
                float4 o;
                o.x = acc[i][j + 0] + bias[tx * TN + j + 0];
                o.y = acc[i][j + 1] + bias[tx * TN + j + 1];
                o.z = acc[i][j + 2] + bias[tx * TN + j + 2];
                o.w = acc[i][j + 3] + bias[tx * TN + j + 3];
                *(float4*)&C[(size_t)gr * BN + tx * TN + j] = o;
            }
        }
    }
}

// paired GEMM: blockIdx.y==0 -> xl written as packed bf16; y==1 -> xr fp32
__global__ __launch_bounds__(256) void k_gemm2(const float* __restrict__ X,
                                               const float* __restrict__ W0,
                                               const float* __restrict__ b0,
                                               unsigned int* __restrict__ C0bf,
                                               const float* __restrict__ W1,
                                               const float* __restrict__ b1,
                                               float* __restrict__ C1, int nrows) {
    constexpr int BM = 128, BK = 32, K = 128, BN = DH;
    constexpr int TM = 8, TN = BN / 16;
    const float* W = blockIdx.y ? W1 : W0;
    const float* bias = blockIdx.y ? b1 : b0;

    __shared__ float Xs[BK][BM + 4];
    __shared__ float Ws[BK][BN + 4];

    const int tid = threadIdx.x;
    const int tx = tid & 15;
    const int ty = tid >> 4;
    const int row0 = blockIdx.x * BM;

    float acc[TM][TN];
    #pragma unroll
    for (int i = 0; i < TM; i++)
        #pragma unroll
        for (int j = 0; j < TN; j++) acc[i][j] = 0.f;

    const int r = tid >> 3;
    const int kq = tid & 7;

    for (int k0 = 0; k0 < K; k0 += BK) {
        #pragma unroll
        for (int rr = 0; rr < BM; rr += 32) {
            int gr = row0 + r + rr;
            float4 v = make_float4(0.f, 0.f, 0.f, 0.f);
            if (gr < nrows) v = *(const float4*)&X[(size_t)gr * K + k0 + kq * 4];
            Xs[kq * 4 + 0][r + rr] = v.x;
            Xs[kq * 4 + 1][r + rr] = v.y;
            Xs[kq * 4 + 2][r + rr] = v.z;
            Xs[kq * 4 + 3][r + rr] = v.w;
        }
        #pragma unroll
        for (int rr = 0; rr < BN; rr += 32) {
            int m = r + rr;
            float4 v = *(const float4*)&W[(size_t)m * K + k0 + kq * 4];
            Ws[kq * 4 + 0][m] = v.x;
            Ws[kq * 4 + 1][m] = v.y;
            Ws[kq * 4 + 2][m] = v.z;
            Ws[kq * 4 + 3][m] = v.w;
        }
        __syncthreads();
        #pragma unroll
        for (int k = 0; k < BK; ++k) {
            float xv[TM], wv[TN];
            #pragma unroll
            for (int i = 0; i < TM; i += 4)
                *(float4*)&xv[i] = *(const float4*)&Xs[k][ty * TM + i];
            #pragma unroll
            for (int j = 0; j < TN; j += 4)
                *(float4*)&wv[j] = *(const float4*)&Ws[k][tx * TN + j];
            #pragma unroll
            for (int i = 0; i < TM; i++)
                #pragma unroll
                for (int j = 0; j < TN; j++) acc[i][j] += xv[i] * wv[j];
        }
        __syncthreads();
    }

    if (blockIdx.y == 0) {
        #pragma unroll
        for (int i = 0; i < TM; i++) {
            int gr = row0 + ty * TM + i;
            if (gr < nrows) {
                uint4 o;
                unsigned int* po = &o.x;
                #pragma unroll
                for (int j = 0; j < TN; j += 2) {
                    float lo = acc[i][j + 0] + bias[tx * TN + j + 0];
                    float hi = acc[i][j + 1] + bias[tx * TN + j + 1];
                    po[j >> 1] = (unsigned int)f2bf(lo) | ((unsigned int)f2bf(hi) << 16);
                }
                *(uint4*)&C0bf[(size_t)gr * (BN / 2) + tx * (TN / 2)] = o;
            }
        }
    } else {
        #pragma unroll
        for (int i = 0; i < TM; i++) {
            int gr = row0 + ty * TM + i;
            if (gr < nrows) {
                #pragma unroll
                for (int j = 0; j < TN; j += 4) {
                    float4 o;
                    o.x = acc[i][j + 0] + bias[tx * TN + j + 0];
                    o.y = acc[i][j + 1] + bias[tx * TN + j + 1];
                    o.z = acc[i][j + 2] + bias[tx * TN + j + 2];
                    o.w = acc[i][j + 3] + bias[tx * TN + j + 3];
                    *(float4*)&C1[(size_t)gr * BN + tx * TN + j] = o;
                }
            }
        }
    }
}

// ---------------- fused per-node softmax + aggregate ----------------
// one wave per node. lane = (slot s = lane>>3, dim-group g = lane&7).
// Each 8-lane cluster owns one edge of the batch and reads its full 256B
// bf16 row contiguously (2x uint4/lane). Lane computes a 16-dim partial
// logit; dim reduce = xor 1,2,4; slot reduce (acc, s) once per node via
// xor 8,16,32. csr_off holds pre-multiplied byte offsets (src*256).

__global__ __launch_bounds__(256) void k_gat_node(const unsigned short* __restrict__ xl16,
                                                  const float* __restrict__ xr,
                                                  const float* __restrict__ att,
                                                  const float* __restrict__ bias,
                                                  const int* __restrict__ csr_off,
                                                  const int* __restrict__ prow,
                                                  const int* __restrict__ deg,
                                                  float* __restrict__ xout) {
    const int lane = threadIdx.x & 63;
    const int n = blockIdx.x * 4 + (threadIdx.x >> 6);
    if (n >= NN) return;

    const int g = lane & 7;       // dim group: dims [g*16, g*16+16)
    const int s = lane >> 3;      // edge slot 0..7
    const int d0 = g * 16;

    // per-lane xr and att slices (16 dims each)
    float xrv[16], atv[16];
    {
        const float4* xr4 = (const float4*)&xr[(size_t)n * DH + d0];
        const float4* at4 = (const float4*)&att[d0];
        #pragma unroll
        for (int j = 0; j < 4; j++) {
            float4 a = xr4[j];
            xrv[4 * j + 0] = a.x; xrv[4 * j + 1] = a.y;
            xrv[4 * j + 2] = a.z; xrv[4 * j + 3] = a.w;
            float4 b = at4[j];
            atv[4 * j + 0] = b.x; atv[4 * j + 1] = b.y;
            atv[4 * j + 2] = b.z; atv[4 * j + 3] = b.w;
        }
    }

    const int p0 = prow[n];
    const int dg = deg[n];
    const int pend = p0 + dg;
    const int pend_pad = p0 + ((dg + 7) & ~7);

    float acc[16];
    #pragma unroll
    for (int j = 0; j < 16; j++) acc[j] = 0.f;
    float ssum = 0.f;

    const char* xlb = (const char*)xl16;
    const int goff = g * 32;

    for (int p = p0; p < pend_pad; p += 8) {
        const int off = csr_off[p + s];            // row byte offset
        const char* rp = xlb + (unsigned int)(off + goff);
        uint4 va = *(const uint4*)rp;
        uint4 vb = *(const uint4*)(rp + 16);
        unsigned int u[8] = {va.x, va.y, va.z, va.w, vb.x, vb.y, vb.z, vb.w};
        float xv[16];
        #pragma unroll
        for (int j = 0; j < 8; j++) {
            xv[2 * j]     = __uint_as_float(u[j] << 16);
            xv[2 * j + 1] = __uint_as_float(u[j] & 0xffff0000u);
        }
        // partial logit over this lane's 16 dims
        float w = 0.f;
        #pragma unroll
        for (int j = 0; j < 16; j++) {
            float z = xv[j] + xrv[j];
            float l = fmaxf(z, NEG * z);
            w = fmaf(l, atv[j], w);
        }
        // reduce over the 8 dim groups (lanes xor 1,2,4)
        w += __shfl_xor(w, 1, 64);
        w += __shfl_xor(w, 2, 64);
        w += __shfl_xor(w, 4, 64);
        // no-max softmax (logits bounded); kill padded edges
        float pe = (p + s < pend) ? __expf(w) : 0.f;
        ssum += pe;
        #pragma unroll
        for (int j = 0; j < 16; j++) acc[j] = fmaf(pe, xv[j], acc[j]);
    }

    // reduce over the 8 slots (lanes xor 8,16,32)
    ssum += __shfl_xor(ssum, 8, 64);
    ssum += __shfl_xor(ssum, 16, 64);
    ssum += __shfl_xor(ssum, 32, 64);
    #pragma unroll
    for (int j = 0; j < 16; j++) {
        acc[j] += __shfl_xor(acc[j], 8, 64);
        acc[j] += __shfl_xor(acc[j], 16, 64);
        acc[j] += __shfl_xor(acc[j], 32, 64);
    }
    const float inv = (ssum > 0.f) ? 1.f / ssum : 0.f;

    // select dim pair (d0 + 2s, d0 + 2s+1) via constant-index cndmask tree
    float b4a[4], b4b[4];
    #pragma unroll
    for (int j = 0; j < 4; j++) {
        b4a[j] = (s & 4) ? acc[2 * (j + 4)]     : acc[2 * j];
        b4b[j] = (s & 4) ? acc[2 * (j + 4) + 1] : acc[2 * j + 1];
    }
    float b2a[2], b2b[2];
    #pragma unroll
    for (int j = 0; j < 2; j++) {
        b2a[j] = (s & 2) ? b4a[j + 2] : b4a[j];
        b2b[j] = (s & 2) ? b4b[j + 2] : b4b[j];
    }
    const float E0 = (s & 1) ? b2a[1] : b2a[0];
    const float E1 = (s & 1) ? b2b[1] : b2b[0];

    const float2 bv = *(const float2*)&bias[d0 + 2 * s];
    const float o0 = fmaxf(fmaf(E0, inv, bv.x), 0.f);
    const float o1 = fmaxf(fmaf(E1, inv, bv.y), 0.f);
    *(float2*)&xout[(size_t)n * DH + d0 + 2 * s] = make_float2(o0, o1);
}

// ---------------- host launch ----------------

static inline size_t align256(size_t x) { return (x + 255) & ~(size_t)255; }

extern "C" void kernel_launch(void* const* d_in, const int* in_sizes, int n_in,
                              void* d_out, int out_size, void* d_ws, size_t ws_size,
                              hipStream_t stream) {
    (void)in_sizes; (void)n_in; (void)out_size; (void)ws_size;

    const float* x   = (const float*)d_in[0];
    const int* ei    = (const int*)d_in[1];
    const float* Wl  = (const float*)d_in[2];
    const float* bl  = (const float*)d_in[3];
    const float* Wr  = (const float*)d_in[4];
    const float* br  = (const float*)d_in[5];
    const float* att = (const float*)d_in[6];
    const float* bias= (const float*)d_in[7];
    const float* W1  = (const float*)d_in[8];
    const float* b1  = (const float*)d_in[9];
    const float* W2  = (const float*)d_in[10];
    const float* b2  = (const float*)d_in[11];
    float* out = (float*)d_out;

    const int* src = ei;
    const int* dst = ei + EE;

    const size_t EP = (size_t)EE + 8 * (size_t)NN;  // padded csr capacity

    char* w = (char*)d_ws;
    float* xA  = (float*)w; w += align256((size_t)NN * DH * 4);
    float* xB  = (float*)w; w += align256((size_t)NN * DH * 4);
    unsigned int* xl16 = (unsigned int*)w; w += align256((size_t)NN * DH * 2);
    float* xrb = (float*)w; w += align256((size_t)NN * DH * 4);
    float* hbuf = (float*)w; w += align256((size_t)NN * DH * 4);
    uint2* pairs = (uint2*)w; w += align256((size_t)EE * 8);
    int* csr_off = (int*)w; w += align256(EP * 4);
    int* prow    = (int*)w; w += align256((size_t)(NN + 1) * 4);
    int* deg     = (int*)w; w += align256((size_t)NN * 4);
    int* cursor  = (int*)w; w += align256((size_t)NN * 4);
    int* bucket_hist   = (int*)w; w += align256(NBK * 4);
    int* bucket_cursor = (int*)w; w += align256(NBK * 4);
    int* bsums   = (int*)w; w += align256(256 * 4);

    const int nb_scan = (NN + 255) / 256;     // 196
    const int nb_edge = (EE + 255) / 256;     // 6250
    const int nb_chunk = (EE + CHUNK - 1) / CHUNK;  // 391
    const int nb_gemm = (NN + 127) / 128;     // 391
    const int nb_node = (NN + 3) / 4;         // 12500

    // ---- build bucketed CSR (by dst, rows padded to 8, byte offsets) ----
    hipMemsetAsync(deg, 0, (size_t)NN * 4, stream);
    hipMemsetAsync(cursor, 0, (size_t)NN * 4, stream);
    hipMemsetAsync(bucket_hist, 0, NBK * 4, stream);
    k_hist<<<nb_chunk, 256, 0, stream>>>(dst, deg, bucket_hist);
    k_scan_bucket<<<1, NBK, 0, stream>>>(bucket_hist, bucket_cursor);
    k_scatter<<<nb_chunk, 256, 0, stream>>>(src, dst, bucket_cursor, pairs);
    k_scan_block<<<nb_scan, 256, 0, stream>>>(deg, prow, bsums, NN);
    k_scan_aux<<<1, 256, 0, stream>>>(bsums, nb_scan);
    k_scan_add<<<nb_scan, 256, 0, stream>>>(prow, bsums, NN);
    k_fill2<<<nb_edge, 256, 0, stream>>>(pairs, prow, cursor, csr_off);
    k_pad<<<nb_scan, 256, 0, stream>>>(deg, prow, csr_off);

    // ---- 3 GATv2 layers ----
    const float* xin = x;
    for (int l = 0; l < 3; ++l) {
        const float* Wl_l = Wl + (size_t)l * DH * DH;
        const float* Wr_l = Wr + (size_t)l * DH * DH;
        const float* bl_l = bl + (size_t)l * DH;
        const float* br_l = br + (size_t)l * DH;
        const float* att_l = att + (size_t)l * DH;
        const float* bias_l = bias + (size_t)l * DH;
        float* xo = (l & 1) ? xB : xA;

        k_gemm2<<<dim3(nb_gemm, 2), 256, 0, stream>>>(xin, Wl_l, bl_l, xl16,
                                                      Wr_l, br_l, xrb, NN);
        k_gat_node<<<nb_node, 256, 0, stream>>>((const unsigned short*)xl16, xrb,
                                                att_l, bias_l, csr_off, prow, deg, xo);
        xin = xo;
    }

    // ---- head MLP ----
    k_gemm<DH><<<nb_gemm, 256, 0, stream>>>(xin, W1, b1, hbuf, NN);
    k_gemm<DOUT><<<nb_gemm, 256, 0, stream>>>(hbuf, W2, b2, out, NN);
}

// Round 6
// 667.756 us; speedup vs baseline: 1.0825x; 1.0825x over previous
//
#include <hip/hip_runtime.h>
#include <hip/hip_bf16.h>

#define NN 50000
#define EE 1600000
#define DH 128
#define DOUT 64
#define NEG 0.2f
#define NBK 256            // bucket array size (used: (NN+255)>>8 = 196)
#define CHUNK 4096         // edges per scatter block

typedef float f16v __attribute__((ext_vector_type(16)));

// ---------------- CSR build (bucketed) ----------------

__global__ __launch_bounds__(256) void k_hist(const int* __restrict__ dst,
                                              int* __restrict__ deg,
                                              int* __restrict__ bucket_hist) {
    __shared__ int lh[NBK];
    lh[threadIdx.x] = 0;
    __syncthreads();
    const int e0 = blockIdx.x * CHUNK;
    #pragma unroll
    for (int k = 0; k < CHUNK / 256; k++) {
        int e = e0 + k * 256 + threadIdx.x;
        if (e < EE) {
            int d = dst[e];
            atomicAdd(&deg[d], 1);
            atomicAdd(&lh[((unsigned)d) >> 8], 1);
        }
    }
    __syncthreads();
    int c = lh[threadIdx.x];
    if (c) atomicAdd(&bucket_hist[threadIdx.x], c);
}

__global__ __launch_bounds__(256) void k_scan_bucket(const int* __restrict__ bucket_hist,
                                                     int* __restrict__ bucket_cursor) {
    __shared__ int tmp[NBK];
    int t = threadIdx.x;
    int v = bucket_hist[t];
    tmp[t] = v;
    __syncthreads();
    #pragma unroll
    for (int off = 1; off < NBK; off <<= 1) {
        int tt = (t >= off) ? tmp[t - off] : 0;
        __syncthreads();
        tmp[t] += tt;
        __syncthreads();
    }
    bucket_cursor[t] = tmp[t] - v;
}

__global__ __launch_bounds__(256) void k_scatter(const int* __restrict__ src,
                                                 const int* __restrict__ dst,
                                                 int* __restrict__ bucket_cursor,
                                                 uint2* __restrict__ pairs) {
    __shared__ int lh[NBK];
    __shared__ int lbase[NBK];
    lh[threadIdx.x] = 0;
    __syncthreads();
    const int e0 = blockIdx.x * CHUNK;
    int dl[CHUNK / 256];
    #pragma unroll
    for (int k = 0; k < CHUNK / 256; k++) {
        int e = e0 + k * 256 + threadIdx.x;
        dl[k] = (e < EE) ? dst[e] : -1;
        if (dl[k] >= 0) atomicAdd(&lh[((unsigned)dl[k]) >> 8], 1);
    }
    __syncthreads();
    int c = lh[threadIdx.x];
    lbase[threadIdx.x] = c ? atomicAdd(&bucket_cursor[threadIdx.x], c) : 0;
    __syncthreads();
    lh[threadIdx.x] = 0;   // reuse as local running cursor
    __syncthreads();
    #pragma unroll
    for (int k = 0; k < CHUNK / 256; k++) {
        int e = e0 + k * 256 + threadIdx.x;
        if (dl[k] >= 0) {
            int b = ((unsigned)dl[k]) >> 8;
            int loc = atomicAdd(&lh[b], 1);
            pairs[lbase[b] + loc] = make_uint2((unsigned)src[e], (unsigned)dl[k]);
        }
    }
}

__global__ __launch_bounds__(256) void k_scan_block(const int* __restrict__ deg,
                                                    int* __restrict__ out,
                                                    int* __restrict__ bsums, int n) {
    __shared__ int tmp[256];
    int i = blockIdx.x * 256 + threadIdx.x;
    int v = (i < n) ? ((deg[i] + 7) & ~7) : 0;
    tmp[threadIdx.x] = v;
    __syncthreads();
    #pragma unroll
    for (int off = 1; off < 256; off <<= 1) {
        int t = (threadIdx.x >= off) ? tmp[threadIdx.x - off] : 0;
        __syncthreads();
        tmp[threadIdx.x] += t;
        __syncthreads();
    }
    if (i < n) out[i] = tmp[threadIdx.x] - v;
    if (threadIdx.x == 255) bsums[blockIdx.x] = tmp[255];
}

__global__ __launch_bounds__(256) void k_scan_aux(int* __restrict__ bsums, int nb) {
    __shared__ int tmp[256];
    int t = threadIdx.x;
    int v = (t < nb) ? bsums[t] : 0;
    tmp[t] = v;
    __syncthreads();
    #pragma unroll
    for (int off = 1; off < 256; off <<= 1) {
        int tt = (t >= off) ? tmp[t - off] : 0;
        __syncthreads();
        tmp[t] += tt;
        __syncthreads();
    }
    if (t < nb) bsums[t] = tmp[t] - v;
}

__global__ __launch_bounds__(256) void k_scan_add(int* __restrict__ out,
                                                  const int* __restrict__ bsums, int n) {
    int i = blockIdx.x * 256 + threadIdx.x;
    if (i < n) out[i] += bsums[blockIdx.x];
}

// final fill: pairs (bucket-ordered) -> csr at padded row positions.
// stores PRE-MULTIPLIED byte offset (src * 256) of the bf16 feature row.
__global__ __launch_bounds__(256) void k_fill2(const uint2* __restrict__ pairs,
                                               const int* __restrict__ prow,
                                               int* __restrict__ cursor,
                                               int* __restrict__ csr_off) {
    int e = blockIdx.x * 256 + threadIdx.x;
    if (e < EE) {
        uint2 pr = pairs[e];
        int d = (int)pr.y;
        int pos = prow[d] + atomicAdd(&cursor[d], 1);
        csr_off[pos] = (int)(pr.x << 8);
    }
}

// pad slots -> offset 0 (node 0's row; logit killed in gat kernel)
__global__ __launch_bounds__(256) void k_pad(const int* __restrict__ deg,
                                             const int* __restrict__ prow,
                                             int* __restrict__ csr_off) {
    int n = blockIdx.x * 256 + threadIdx.x;
    if (n < NN) {
        int d = deg[n];
        int p = prow[n] + d;
        int e = prow[n] + ((d + 7) & ~7);
        for (; p < e; ++p) csr_off[p] = 0;
    }
}

// ---------------- helpers ----------------

static __device__ __forceinline__ unsigned short f2bf(float f) {
    unsigned int u = __float_as_uint(f);
    unsigned int r = (u + 0x7fffu + ((u >> 16) & 1u)) >> 16;  // RNE
    return (unsigned short)r;
}

// ---------------- GEMM: C[n,m] = sum_k X[n,k]*W[m,k] + b[m], K=128 ----------------

template <int BN>
__global__ __launch_bounds__(256) void k_gemm(const float* __restrict__ X,
                                              const float* __restrict__ W,
                                              const float* __restrict__ bias,
                                              float* __restrict__ C, int nrows) {
    constexpr int BM = 128, BK = 32, K = 128;
    constexpr int TM = 8;
    constexpr int TN = BN / 16;
    __shared__ float Xs[BK][BM + 4];
    __shared__ float Ws[BK][BN + 4];

    const int tid = threadIdx.x;
    const int tx = tid & 15;
    const int ty = tid >> 4;
    const int row0 = blockIdx.x * BM;

    float acc[TM][TN];
    #pragma unroll
    for (int i = 0; i < TM; i++)
        #pragma unroll
        for (int j = 0; j < TN; j++) acc[i][j] = 0.f;

    const int r = tid >> 3;
    const int kq = tid & 7;

    for (int k0 = 0; k0 < K; k0 += BK) {
        #pragma unroll
        for (int rr = 0; rr < BM; rr += 32) {
            int gr = row0 + r + rr;
            float4 v = make_float4(0.f, 0.f, 0.f, 0.f);
            if (gr < nrows) v = *(const float4*)&X[(size_t)gr * K + k0 + kq * 4];
            Xs[kq * 4 + 0][r + rr] = v.x;
            Xs[kq * 4 + 1][r + rr] = v.y;
            Xs[kq * 4 + 2][r + rr] = v.z;
            Xs[kq * 4 + 3][r + rr] = v.w;
        }
        #pragma unroll
        for (int rr = 0; rr < BN; rr += 32) {
            int m = r + rr;
            float4 v = *(const float4*)&W[(size_t)m * K + k0 + kq * 4];
            Ws[kq * 4 + 0][m] = v.x;
            Ws[kq * 4 + 1][m] = v.y;
            Ws[kq * 4 + 2][m] = v.z;
            Ws[kq * 4 + 3][m] = v.w;
        }
        __syncthreads();
        #pragma unroll
        for (int k = 0; k < BK; ++k) {
            float xv[TM], wv[TN];
            #pragma unroll
            for (int i = 0; i < TM; i += 4)
                *(float4*)&xv[i] = *(const float4*)&Xs[k][ty * TM + i];
            #pragma unroll
            for (int j = 0; j < TN; j += 4)
                *(float4*)&wv[j] = *(const float4*)&Ws[k][tx * TN + j];
            #pragma unroll
            for (int i = 0; i < TM; i++)
                #pragma unroll
                for (int j = 0; j < TN; j++) acc[i][j] += xv[i] * wv[j];
        }
        __syncthreads();
    }

    #pragma unroll
    for (int i = 0; i < TM; i++) {
        int gr = row0 + ty * TM + i;
        if (gr < nrows) {
            #pragma unroll
            for (int j = 0; j < TN; j += 4) {
                float4 o;
                o.x = acc[i][j + 0] + bias[tx * TN + j + 0];
                o.y = acc[i][j + 1] + bias[tx * TN + j + 1];
                o.z = acc[i][j + 2] + bias[tx * TN + j + 2];
                o.w = acc[i][j + 3] + bias[tx * TN + j + 3];
                *(float4*)&C[(size_t)gr * BN + tx * TN + j] = o;
            }
        }
    }
}

// paired GEMM: blockIdx.y==0 -> xl written as packed bf16; y==1 -> xr fp32
__global__ __launch_bounds__(256) void k_gemm2(const float* __restrict__ X,
                                               const float* __restrict__ W0,
                                               const float* __restrict__ b0,
                                               unsigned int* __restrict__ C0bf,
                                               const float* __restrict__ W1,
                                               const float* __restrict__ b1,
                                               float* __restrict__ C1, int nrows) {
    constexpr int BM = 128, BK = 32, K = 128, BN = DH;
    constexpr int TM = 8, TN = BN / 16;
    const float* W = blockIdx.y ? W1 : W0;
    const float* bias = blockIdx.y ? b1 : b0;

    __shared__ float Xs[BK][BM + 4];
    __shared__ float Ws[BK][BN + 4];

    const int tid = threadIdx.x;
    const int tx = tid & 15;
    const int ty = tid >> 4;
    const int row0 = blockIdx.x * BM;

    float acc[TM][TN];
    #pragma unroll
    for (int i = 0; i < TM; i++)
        #pragma unroll
        for (int j = 0; j < TN; j++) acc[i][j] = 0.f;

    const int r = tid >> 3;
    const int kq = tid & 7;

    for (int k0 = 0; k0 < K; k0 += BK) {
        #pragma unroll
        for (int rr = 0; rr < BM; rr += 32) {
            int gr = row0 + r + rr;
            float4 v = make_float4(0.f, 0.f, 0.f, 0.f);
            if (gr < nrows) v = *(const float4*)&X[(size_t)gr * K + k0 + kq * 4];
            Xs[kq * 4 + 0][r + rr] = v.x;
            Xs[kq * 4 + 1][r + rr] = v.y;
            Xs[kq * 4 + 2][r + rr] = v.z;
            Xs[kq * 4 + 3][r + rr] = v.w;
        }
        #pragma unroll
        for (int rr = 0; rr < BN; rr += 32) {
            int m = r + rr;
            float4 v = *(const float4*)&W[(size_t)m * K + k0 + kq * 4];
            Ws[kq * 4 + 0][m] = v.x;
            Ws[kq * 4 + 1][m] = v.y;
            Ws[kq * 4 + 2][m] = v.z;
            Ws[kq * 4 + 3][m] = v.w;
        }
        __syncthreads();
        #pragma unroll
        for (int k = 0; k < BK; ++k) {
            float xv[TM], wv[TN];
            #pragma unroll
            for (int i = 0; i < TM; i += 4)
                *(float4*)&xv[i] = *(const float4*)&Xs[k][ty * TM + i];
            #pragma unroll
            for (int j = 0; j < TN; j += 4)
                *(float4*)&wv[j] = *(const float4*)&Ws[k][tx * TN + j];
            #pragma unroll
            for (int i = 0; i < TM; i++)
                #pragma unroll
                for (int j = 0; j < TN; j++) acc[i][j] += xv[i] * wv[j];
        }
        __syncthreads();
    }

    if (blockIdx.y == 0) {
        #pragma unroll
        for (int i = 0; i < TM; i++) {
            int gr = row0 + ty * TM + i;
            if (gr < nrows) {
                uint4 o;
                unsigned int* po = &o.x;
                #pragma unroll
                for (int j = 0; j < TN; j += 2) {
                    float lo = acc[i][j + 0] + bias[tx * TN + j + 0];
                    float hi = acc[i][j + 1] + bias[tx * TN + j + 1];
                    po[j >> 1] = (unsigned int)f2bf(lo) | ((unsigned int)f2bf(hi) << 16);
                }
                *(uint4*)&C0bf[(size_t)gr * (BN / 2) + tx * (TN / 2)] = o;
            }
        }
    } else {
        #pragma unroll
        for (int i = 0; i < TM; i++) {
            int gr = row0 + ty * TM + i;
            if (gr < nrows) {
                #pragma unroll
                for (int j = 0; j < TN; j += 4) {
                    float4 o;
                    o.x = acc[i][j + 0] + bias[tx * TN + j + 0];
                    o.y = acc[i][j + 1] + bias[tx * TN + j + 1];
                    o.z = acc[i][j + 2] + bias[tx * TN + j + 2];
                    o.w = acc[i][j + 3] + bias[tx * TN + j + 3];
                    *(float4*)&C1[(size_t)gr * BN + tx * TN + j] = o;
                }
            }
        }
    }
}

// ---------------- fused per-node softmax + aggregate ----------------
// one wave per node. lane = (slot s = lane>>3, dim-group g = lane&7).
// Each 8-lane cluster owns one edge; lane reads 32 contiguous bytes (16 bf16
// dims) of the edge's row. Dim reduce = shfl_xor 1,2,4; slot reduce once per
// node via shfl_xor 8,16,32. ALL per-lane state is ext_vector (SSA regs) --
// no alloca, so AMDGPUPromoteAlloca cannot demote to LDS (R5 regression).
// Epilogue: cndmask pair-select + 8x8 transpose shfl -> linear float2 store.

__global__ __launch_bounds__(256) void k_gat_node(const unsigned short* __restrict__ xl16,
                                                  const float* __restrict__ xr,
                                                  const float* __restrict__ att,
                                                  const float* __restrict__ bias,
                                                  const int* __restrict__ csr_off,
                                                  const int* __restrict__ prow,
                                                  const int* __restrict__ deg,
                                                  float* __restrict__ xout) {
    const int lane = threadIdx.x & 63;
    const int n = blockIdx.x * 4 + (threadIdx.x >> 6);
    if (n >= NN) return;

    const int g = lane & 7;       // dim group: dims [g*16, g*16+16)
    const int s = lane >> 3;      // edge slot 0..7
    const int d0 = g * 16;

    f16v xrv, atv;
    {
        const float4* xr4 = (const float4*)&xr[(size_t)n * DH + d0];
        const float4* at4 = (const float4*)&att[d0];
        #pragma unroll
        for (int j = 0; j < 4; j++) {
            float4 a = xr4[j];
            xrv[4 * j + 0] = a.x; xrv[4 * j + 1] = a.y;
            xrv[4 * j + 2] = a.z; xrv[4 * j + 3] = a.w;
            float4 b = at4[j];
            atv[4 * j + 0] = b.x; atv[4 * j + 1] = b.y;
            atv[4 * j + 2] = b.z; atv[4 * j + 3] = b.w;
        }
    }

    const int p0 = prow[n];
    const int dg = deg[n];
    const int pend = p0 + dg;
    const int pend_pad = p0 + ((dg + 7) & ~7);

    f16v acc = {};
    float ssum = 0.f;

    const char* xlb = (const char*)xl16;
    const int goff = g * 32;

    for (int p = p0; p < pend_pad; p += 8) {
        const int off = csr_off[p + s];            // row byte offset (src*256)
        const char* rp = xlb + (unsigned int)(off + goff);
        uint4 va = *(const uint4*)rp;
        uint4 vb = *(const uint4*)(rp + 16);
        f16v xv;
        xv[0]  = __uint_as_float(va.x << 16);
        xv[1]  = __uint_as_float(va.x & 0xffff0000u);
        xv[2]  = __uint_as_float(va.y << 16);
        xv[3]  = __uint_as_float(va.y & 0xffff0000u);
        xv[4]  = __uint_as_float(va.z << 16);
        xv[5]  = __uint_as_float(va.z & 0xffff0000u);
        xv[6]  = __uint_as_float(va.w << 16);
        xv[7]  = __uint_as_float(va.w & 0xffff0000u);
        xv[8]  = __uint_as_float(vb.x << 16);
        xv[9]  = __uint_as_float(vb.x & 0xffff0000u);
        xv[10] = __uint_as_float(vb.y << 16);
        xv[11] = __uint_as_float(vb.y & 0xffff0000u);
        xv[12] = __uint_as_float(vb.z << 16);
        xv[13] = __uint_as_float(vb.z & 0xffff0000u);
        xv[14] = __uint_as_float(vb.w << 16);
        xv[15] = __uint_as_float(vb.w & 0xffff0000u);

        float w = 0.f;
        #pragma unroll
        for (int j = 0; j < 16; j++) {
            float z = xv[j] + xrv[j];
            float l = fmaxf(z, NEG * z);
            w = fmaf(l, atv[j], w);
        }
        // reduce over the 8 dim groups
        w += __shfl_xor(w, 1, 64);
        w += __shfl_xor(w, 2, 64);
        w += __shfl_xor(w, 4, 64);
        // no-max softmax (logits bounded); kill padded edges
        float pe = (p + s < pend) ? __expf(w) : 0.f;
        ssum += pe;
        #pragma unroll
        for (int j = 0; j < 16; j++) acc[j] = fmaf(pe, xv[j], acc[j]);
    }

    // reduce over the 8 slots
    ssum += __shfl_xor(ssum, 8, 64);
    ssum += __shfl_xor(ssum, 16, 64);
    ssum += __shfl_xor(ssum, 32, 64);
    #pragma unroll
    for (int j = 0; j < 16; j++) {
        acc[j] += __shfl_xor(acc[j], 8, 64);
        acc[j] += __shfl_xor(acc[j], 16, 64);
        acc[j] += __shfl_xor(acc[j], 32, 64);
    }
    const float inv = (ssum > 0.f) ? 1.f / ssum : 0.f;

    // pair-select (2s, 2s+1) via cndmask tree (scalar SSA temps)
    float a0 = (s & 1) ? acc[2]  : acc[0];
    float a1 = (s & 1) ? acc[6]  : acc[4];
    float a2 = (s & 1) ? acc[10] : acc[8];
    float a3 = (s & 1) ? acc[14] : acc[12];
    float b0 = (s & 2) ? a1 : a0;
    float b1 = (s & 2) ? a3 : a2;
    const float E0 = (s & 4) ? b1 : b0;
    float c0 = (s & 1) ? acc[3]  : acc[1];
    float c1 = (s & 1) ? acc[7]  : acc[5];
    float c2 = (s & 1) ? acc[11] : acc[9];
    float c3 = (s & 1) ? acc[15] : acc[13];
    float e0 = (s & 2) ? c1 : c0;
    float e1 = (s & 2) ? c3 : c2;
    const float E1 = (s & 4) ? e1 : e0;

    // 8x8 transpose shuffle: lane l pulls from lane (l&7)*8 + (l>>3)
    // -> lane l holds dims (2l, 2l+1); store is fully linear.
    const int srcl = ((lane & 7) << 3) | (lane >> 3);
    const float F0 = __shfl(E0, srcl, 64);
    const float F1 = __shfl(E1, srcl, 64);

    const float2 bv = *(const float2*)&bias[2 * lane];
    const float o0 = fmaxf(fmaf(F0, inv, bv.x), 0.f);
    const float o1 = fmaxf(fmaf(F1, inv, bv.y), 0.f);
    *(float2*)&xout[(size_t)n * DH + 2 * lane] = make_float2(o0, o1);
}

// ---------------- host launch ----------------

static inline size_t align256(size_t x) { return (x + 255) & ~(size_t)255; }

extern "C" void kernel_launch(void* const* d_in, const int* in_sizes, int n_in,
                              void* d_out, int out_size, void* d_ws, size_t ws_size,
                              hipStream_t stream) {
    (void)in_sizes; (void)n_in; (void)out_size; (void)ws_size;

    const float* x   = (const float*)d_in[0];
    const int* ei    = (const int*)d_in[1];
    const float* Wl  = (const float*)d_in[2];
    const float* bl  = (const float*)d_in[3];
    const float* Wr  = (const float*)d_in[4];
    const float* br  = (const float*)d_in[5];
    const float* att = (const float*)d_in[6];
    const float* bias= (const float*)d_in[7];
    const float* W1  = (const float*)d_in[8];
    const float* b1  = (const float*)d_in[9];
    const float* W2  = (const float*)d_in[10];
    const float* b2  = (const float*)d_in[11];
    float* out = (float*)d_out;

    const int* src = ei;
    const int* dst = ei + EE;

    const size_t EP = (size_t)EE + 8 * (size_t)NN;  // padded csr capacity

    char* w = (char*)d_ws;
    float* xA  = (float*)w; w += align256((size_t)NN * DH * 4);
    float* xB  = (float*)w; w += align256((size_t)NN * DH * 4);
    unsigned int* xl16 = (unsigned int*)w; w += align256((size_t)NN * DH * 2);
    float* xrb = (float*)w; w += align256((size_t)NN * DH * 4);
    float* hbuf = (float*)w; w += align256((size_t)NN * DH * 4);
    uint2* pairs = (uint2*)w; w += align256((size_t)EE * 8);
    int* csr_off = (int*)w; w += align256(EP * 4);
    int* prow    = (int*)w; w += align256((size_t)(NN + 1) * 4);
    int* deg     = (int*)w; w += align256((size_t)NN * 4);
    int* cursor  = (int*)w; w += align256((size_t)NN * 4);
    int* bucket_hist   = (int*)w; w += align256(NBK * 4);
    int* bucket_cursor = (int*)w; w += align256(NBK * 4);
    int* bsums   = (int*)w; w += align256(256 * 4);

    const int nb_scan = (NN + 255) / 256;     // 196
    const int nb_edge = (EE + 255) / 256;     // 6250
    const int nb_chunk = (EE + CHUNK - 1) / CHUNK;  // 391
    const int nb_gemm = (NN + 127) / 128;     // 391
    const int nb_node = (NN + 3) / 4;         // 12500

    // ---- build bucketed CSR (by dst, rows padded to 8, byte offsets) ----
    hipMemsetAsync(deg, 0, (size_t)NN * 4, stream);
    hipMemsetAsync(cursor, 0, (size_t)NN * 4, stream);
    hipMemsetAsync(bucket_hist, 0, NBK * 4, stream);
    k_hist<<<nb_chunk, 256, 0, stream>>>(dst, deg, bucket_hist);
    k_scan_bucket<<<1, NBK, 0, stream>>>(bucket_hist, bucket_cursor);
    k_scatter<<<nb_chunk, 256, 0, stream>>>(src, dst, bucket_cursor, pairs);
    k_scan_block<<<nb_scan, 256, 0, stream>>>(deg, prow, bsums, NN);
    k_scan_aux<<<1, 256, 0, stream>>>(bsums, nb_scan);
    k_scan_add<<<nb_scan, 256, 0, stream>>>(prow, bsums, NN);
    k_fill2<<<nb_edge, 256, 0, stream>>>(pairs, prow, cursor, csr_off);
    k_pad<<<nb_scan, 256, 0, stream>>>(deg, prow, csr_off);

    // ---- 3 GATv2 layers ----
    const float* xin = x;
    for (int l = 0; l < 3; ++l) {
        const float* Wl_l = Wl + (size_t)l * DH * DH;
        const float* Wr_l = Wr + (size_t)l * DH * DH;
        const float* bl_l = bl + (size_t)l * DH;
        const float* br_l = br + (size_t)l * DH;
        const float* att_l = att + (size_t)l * DH;
        const float* bias_l = bias + (size_t)l * DH;
        float* xo = (l & 1) ? xB : xA;

        k_gemm2<<<dim3(nb_gemm, 2), 256, 0, stream>>>(xin, Wl_l, bl_l, xl16,
                                                      Wr_l, br_l, xrb, NN);
        k_gat_node<<<nb_node, 256, 0, stream>>>((const unsigned short*)xl16, xrb,
                                                att_l, bias_l, csr_off, prow, deg, xo);
        xin = xo;
    }

    // ---- head MLP ----
    k_gemm<DH><<<nb_gemm, 256, 0, stream>>>(xin, W1, b1, hbuf, NN);
    k_gemm<DOUT><<<nb_gemm, 256, 0, stream>>>(hbuf, W2, b2, out, NN);
}

// Round 7
// 616.776 us; speedup vs baseline: 1.1720x; 1.0827x over previous
//
#include <hip/hip_runtime.h>
#include <hip/hip_bf16.h>

#define NN 50000
#define EE 1600000
#define DH 128
#define DOUT 64
#define NEG 0.2f
#define NBK 256            // bucket array size (used: (NN+255)>>8 = 196)
#define CHUNK 4096         // edges per scatter block

typedef float f16v __attribute__((ext_vector_type(16)));
typedef short bf16x8 __attribute__((ext_vector_type(8)));
typedef float f32x4 __attribute__((ext_vector_type(4)));

// ---------------- CSR build (bucketed) ----------------

__global__ __launch_bounds__(256) void k_hist(const int* __restrict__ dst,
                                              int* __restrict__ deg,
                                              int* __restrict__ bucket_hist) {
    __shared__ int lh[NBK];
    lh[threadIdx.x] = 0;
    __syncthreads();
    const int e0 = blockIdx.x * CHUNK;
    #pragma unroll
    for (int k = 0; k < CHUNK / 256; k++) {
        int e = e0 + k * 256 + threadIdx.x;
        if (e < EE) {
            int d = dst[e];
            atomicAdd(&deg[d], 1);
            atomicAdd(&lh[((unsigned)d) >> 8], 1);
        }
    }
    __syncthreads();
    int c = lh[threadIdx.x];
    if (c) atomicAdd(&bucket_hist[threadIdx.x], c);
}

__global__ __launch_bounds__(256) void k_scan_bucket(const int* __restrict__ bucket_hist,
                                                     int* __restrict__ bucket_cursor) {
    __shared__ int tmp[NBK];
    int t = threadIdx.x;
    int v = bucket_hist[t];
    tmp[t] = v;
    __syncthreads();
    #pragma unroll
    for (int off = 1; off < NBK; off <<= 1) {
        int tt = (t >= off) ? tmp[t - off] : 0;
        __syncthreads();
        tmp[t] += tt;
        __syncthreads();
    }
    bucket_cursor[t] = tmp[t] - v;
}

__global__ __launch_bounds__(256) void k_scatter(const int* __restrict__ src,
                                                 const int* __restrict__ dst,
                                                 int* __restrict__ bucket_cursor,
                                                 uint2* __restrict__ pairs) {
    __shared__ int lh[NBK];
    __shared__ int lbase[NBK];
    lh[threadIdx.x] = 0;
    __syncthreads();
    const int e0 = blockIdx.x * CHUNK;
    int dl[CHUNK / 256];
    #pragma unroll
    for (int k = 0; k < CHUNK / 256; k++) {
        int e = e0 + k * 256 + threadIdx.x;
        dl[k] = (e < EE) ? dst[e] : -1;
        if (dl[k] >= 0) atomicAdd(&lh[((unsigned)dl[k]) >> 8], 1);
    }
    __syncthreads();
    int c = lh[threadIdx.x];
    lbase[threadIdx.x] = c ? atomicAdd(&bucket_cursor[threadIdx.x], c) : 0;
    __syncthreads();
    lh[threadIdx.x] = 0;   // reuse as local running cursor
    __syncthreads();
    #pragma unroll
    for (int k = 0; k < CHUNK / 256; k++) {
        int e = e0 + k * 256 + threadIdx.x;
        if (dl[k] >= 0) {
            int b = ((unsigned)dl[k]) >> 8;
            int loc = atomicAdd(&lh[b], 1);
            pairs[lbase[b] + loc] = make_uint2((unsigned)src[e], (unsigned)dl[k]);
        }
    }
}

__global__ __launch_bounds__(256) void k_scan_block(const int* __restrict__ deg,
                                                    int* __restrict__ out,
                                                    int* __restrict__ bsums, int n) {
    __shared__ int tmp[256];
    int i = blockIdx.x * 256 + threadIdx.x;
    int v = (i < n) ? ((deg[i] + 7) & ~7) : 0;
    tmp[threadIdx.x] = v;
    __syncthreads();
    #pragma unroll
    for (int off = 1; off < 256; off <<= 1) {
        int t = (threadIdx.x >= off) ? tmp[threadIdx.x - off] : 0;
        __syncthreads();
        tmp[threadIdx.x] += t;
        __syncthreads();
    }
    if (i < n) out[i] = tmp[threadIdx.x] - v;
    if (threadIdx.x == 255) bsums[blockIdx.x] = tmp[255];
}

__global__ __launch_bounds__(256) void k_scan_aux(int* __restrict__ bsums, int nb) {
    __shared__ int tmp[256];
    int t = threadIdx.x;
    int v = (t < nb) ? bsums[t] : 0;
    tmp[t] = v;
    __syncthreads();
    #pragma unroll
    for (int off = 1; off < 256; off <<= 1) {
        int tt = (t >= off) ? tmp[t - off] : 0;
        __syncthreads();
        tmp[t] += tt;
        __syncthreads();
    }
    if (t < nb) bsums[t] = tmp[t] - v;
}

__global__ __launch_bounds__(256) void k_scan_add(int* __restrict__ out,
                                                  const int* __restrict__ bsums, int n) {
    int i = blockIdx.x * 256 + threadIdx.x;
    if (i < n) out[i] += bsums[blockIdx.x];
}

// final fill: pairs (bucket-ordered) -> csr at padded row positions.
// stores PRE-MULTIPLIED byte offset (src * 256) of the bf16 feature row.
__global__ __launch_bounds__(256) void k_fill2(const uint2* __restrict__ pairs,
                                               const int* __restrict__ prow,
                                               int* __restrict__ cursor,
                                               int* __restrict__ csr_off) {
    int e = blockIdx.x * 256 + threadIdx.x;
    if (e < EE) {
        uint2 pr = pairs[e];
        int d = (int)pr.y;
        int pos = prow[d] + atomicAdd(&cursor[d], 1);
        csr_off[pos] = (int)(pr.x << 8);
    }
}

// pad slots -> offset 0 (node 0's row; logit killed in gat kernel)
__global__ __launch_bounds__(256) void k_pad(const int* __restrict__ deg,
                                             const int* __restrict__ prow,
                                             int* __restrict__ csr_off) {
    int n = blockIdx.x * 256 + threadIdx.x;
    if (n < NN) {
        int d = deg[n];
        int p = prow[n] + d;
        int e = prow[n] + ((d + 7) & ~7);
        for (; p < e; ++p) csr_off[p] = 0;
    }
}

// ---------------- helpers ----------------

static __device__ __forceinline__ unsigned int f2bf(float f) {
    unsigned int u = __float_as_uint(f);
    return (u + 0x7fffu + ((u >> 16) & 1u)) >> 16;  // RNE
}
static __device__ __forceinline__ unsigned int pack2bf(float lo, float hi) {
    return f2bf(lo) | (f2bf(hi) << 16);
}

// ---------------- MFMA GEMM: C[n,m] = sum_k X[n,k]*W[m,k] + b[m] ----------------
// K = 128, A = X rows (fp32 -> bf16 on stage), B = W rows (fp32 -> bf16).
// LDS layout [kc][kg][row][8]: fragment ds_read_b128 is contiguous per
// 16-lane group (conflict-free, no swizzle). 256 threads = 4 waves.
// BN=128: wave = 64x64 (4x4 frags). BN=64: wave = 32x64 (2x4 frags).
// blockIdx.y==0 && C0bf: bf16-packed out (W0,b0); else fp32 out (Wy,by).

template <int BN>
__global__ __launch_bounds__(256) void k_mfma(const float* __restrict__ X,
                                              const float* __restrict__ W0,
                                              const float* __restrict__ b0,
                                              unsigned int* __restrict__ C0bf,
                                              const float* __restrict__ W1,
                                              const float* __restrict__ b1,
                                              float* __restrict__ C1,
                                              int nrows) {
    constexpr int MF = (BN == 128) ? 4 : 2;   // m-fragments per wave
    constexpr int NF = 4;                     // n-fragments per wave
    __shared__ __align__(16) unsigned short As[4][4][128][8];
    __shared__ __align__(16) unsigned short Bs[4][4][BN][8];

    const int tid = threadIdx.x;
    const int row0 = blockIdx.x * 128;
    const bool bfout = (blockIdx.y == 0) && (C0bf != nullptr);
    const float* W = (blockIdx.y == 0) ? W0 : W1;
    const float* bias = (blockIdx.y == 0) ? b0 : b1;

    // stage A: 128 rows x 128 cols fp32 -> bf16
    #pragma unroll
    for (int i = 0; i < 16; i++) {
        int L = i * 256 + tid;          // 0..4095
        int r = L >> 5, kq = L & 31;    // kq*4 = k
        int gr = row0 + r;
        float4 v = make_float4(0.f, 0.f, 0.f, 0.f);
        if (gr < nrows) v = *(const float4*)&X[(size_t)gr * 128 + kq * 4];
        int k = kq * 4;
        int kc = k >> 5, kg = (k >> 3) & 3, e = k & 7;
        *(uint2*)&As[kc][kg][r][e] = make_uint2(pack2bf(v.x, v.y), pack2bf(v.z, v.w));
    }
    // stage B: BN rows x 128 cols fp32 -> bf16
    #pragma unroll
    for (int i = 0; i < (BN * 32) / 256; i++) {
        int L = i * 256 + tid;
        int r = L >> 5, kq = L & 31;
        float4 v = *(const float4*)&W[(size_t)r * 128 + kq * 4];
        int k = kq * 4;
        int kc = k >> 5, kg = (k >> 3) & 3, e = k & 7;
        *(uint2*)&Bs[kc][kg][r][e] = make_uint2(pack2bf(v.x, v.y), pack2bf(v.z, v.w));
    }
    __syncthreads();

    const int w = tid >> 6;
    const int lane = tid & 63;
    const int lr = lane & 15;
    const int kg = lane >> 4;
    const int rowbase = (BN == 128) ? (w >> 1) * 64 : w * 32;
    const int colbase = (BN == 128) ? (w & 1) * 64 : 0;

    f32x4 acc[MF][NF];
    #pragma unroll
    for (int i = 0; i < MF; i++)
        #pragma unroll
        for (int j = 0; j < NF; j++) acc[i][j] = (f32x4){0.f, 0.f, 0.f, 0.f};

    #pragma unroll
    for (int kc = 0; kc < 4; kc++) {
        bf16x8 af[MF], bfr[NF];
        #pragma unroll
        for (int i = 0; i < MF; i++)
            af[i] = *(const bf16x8*)&As[kc][kg][rowbase + i * 16 + lr][0];
        #pragma unroll
        for (int j = 0; j < NF; j++)
            bfr[j] = *(const bf16x8*)&Bs[kc][kg][colbase + j * 16 + lr][0];
        #pragma unroll
        for (int i = 0; i < MF; i++)
            #pragma unroll
            for (int j = 0; j < NF; j++)
                acc[i][j] = __builtin_amdgcn_mfma_f32_16x16x32_bf16(af[i], bfr[j],
                                                                    acc[i][j], 0, 0, 0);
    }

    // epilogue: C/D layout col = lane&15, row = (lane>>4)*4 + reg
    #pragma unroll
    for (int i = 0; i < MF; i++) {
        #pragma unroll
        for (int reg = 0; reg < 4; reg++) {
            int row = rowbase + i * 16 + (lane >> 4) * 4 + reg;
            int gr = row0 + row;
            if (gr < nrows) {
                #pragma unroll
                for (int j = 0; j < NF; j++) {
                    int col = colbase + j * 16 + lr;
                    float v = acc[i][j][reg] + bias[col];
                    if (bfout) {
                        float vn = __shfl_xor(v, 1, 64);
                        if (!(lane & 1)) {
                            C0bf[(size_t)gr * (BN / 2) + (col >> 1)] = pack2bf(v, vn);
                        }
                    } else {
                        C1[(size_t)gr * BN + col] = v;
                    }
                }
            }
        }
    }
}

// ---------------- fused per-node softmax + aggregate ----------------
// one wave per node. lane = (slot s = lane>>3, dim-group g = lane&7).
// 16 edges per iteration: each 8-lane cluster handles edges s and s+8
// (4 gather loads + 2 index loads in flight). Dim reduce = shfl_xor 1,2,4;
// slot reduce once per node. All state in ext_vector SSA regs (no alloca).

__global__ __launch_bounds__(256) void k_gat_node(const unsigned short* __restrict__ xl16,
                                                  const float* __restrict__ xr,
                                                  const float* __restrict__ att,
                                                  const float* __restrict__ bias,
                                                  const int* __restrict__ csr_off,
                                                  const int* __restrict__ prow,
                                                  const int* __restrict__ deg,
                                                  float* __restrict__ xout) {
    const int lane = threadIdx.x & 63;
    const int n = blockIdx.x * 4 + (threadIdx.x >> 6);
    if (n >= NN) return;

    const int g = lane & 7;       // dim group: dims [g*16, g*16+16)
    const int s = lane >> 3;      // edge slot 0..7
    const int d0 = g * 16;

    f16v xrv, atv;
    {
        const float4* xr4 = (const float4*)&xr[(size_t)n * DH + d0];
        const float4* at4 = (const float4*)&att[d0];
        #pragma unroll
        for (int j = 0; j < 4; j++) {
            float4 a = xr4[j];
            xrv[4 * j + 0] = a.x; xrv[4 * j + 1] = a.y;
            xrv[4 * j + 2] = a.z; xrv[4 * j + 3] = a.w;
            float4 b = at4[j];
            atv[4 * j + 0] = b.x; atv[4 * j + 1] = b.y;
            atv[4 * j + 2] = b.z; atv[4 * j + 3] = b.w;
        }
    }

    const int p0 = prow[n];
    const int dg = deg[n];
    const int pend = p0 + dg;
    const int pend_pad = p0 + ((dg + 7) & ~7);

    f16v acc = {};
    float ssum = 0.f;

    const char* xlb = (const char*)xl16;
    const int goff = g * 32;

    int p = p0;
    for (; p + 16 <= pend_pad; p += 16) {
        const int off0 = csr_off[p + s];
        const int off1 = csr_off[p + 8 + s];
        const char* rp0 = xlb + (unsigned int)(off0 + goff);
        const char* rp1 = xlb + (unsigned int)(off1 + goff);
        uint4 va0 = *(const uint4*)rp0;
        uint4 vb0 = *(const uint4*)(rp0 + 16);
        uint4 va1 = *(const uint4*)rp1;
        uint4 vb1 = *(const uint4*)(rp1 + 16);
        f16v xv0, xv1;
        xv0[0]  = __uint_as_float(va0.x << 16); xv0[1]  = __uint_as_float(va0.x & 0xffff0000u);
        xv0[2]  = __uint_as_float(va0.y << 16); xv0[3]  = __uint_as_float(va0.y & 0xffff0000u);
        xv0[4]  = __uint_as_float(va0.z << 16); xv0[5]  = __uint_as_float(va0.z & 0xffff0000u);
        xv0[6]  = __uint_as_float(va0.w << 16); xv0[7]  = __uint_as_float(va0.w & 0xffff0000u);
        xv0[8]  = __uint_as_float(vb0.x << 16); xv0[9]  = __uint_as_float(vb0.x & 0xffff0000u);
        xv0[10] = __uint_as_float(vb0.y << 16); xv0[11] = __uint_as_float(vb0.y & 0xffff0000u);
        xv0[12] = __uint_as_float(vb0.z << 16); xv0[13] = __uint_as_float(vb0.z & 0xffff0000u);
        xv0[14] = __uint_as_float(vb0.w << 16); xv0[15] = __uint_as_float(vb0.w & 0xffff0000u);
        xv1[0]  = __uint_as_float(va1.x << 16); xv1[1]  = __uint_as_float(va1.x & 0xffff0000u);
        xv1[2]  = __uint_as_float(va1.y << 16); xv1[3]  = __uint_as_float(va1.y & 0xffff0000u);
        xv1[4]  = __uint_as_float(va1.z << 16); xv1[5]  = __uint_as_float(va1.z & 0xffff0000u);
        xv1[6]  = __uint_as_float(va1.w << 16); xv1[7]  = __uint_as_float(va1.w & 0xffff0000u);
        xv1[8]  = __uint_as_float(vb1.x << 16); xv1[9]  = __uint_as_float(vb1.x & 0xffff0000u);
        xv1[10] = __uint_as_float(vb1.y << 16); xv1[11] = __uint_as_float(vb1.y & 0xffff0000u);
        xv1[12] = __uint_as_float(vb1.z << 16); xv1[13] = __uint_as_float(vb1.z & 0xffff0000u);
        xv1[14] = __uint_as_float(vb1.w << 16); xv1[15] = __uint_as_float(vb1.w & 0xffff0000u);

        float w0 = 0.f, w1 = 0.f;
        #pragma unroll
        for (int j = 0; j < 16; j++) {
            float z0 = xv0[j] + xrv[j];
            float l0 = fmaxf(z0, NEG * z0);
            w0 = fmaf(l0, atv[j], w0);
            float z1 = xv1[j] + xrv[j];
            float l1 = fmaxf(z1, NEG * z1);
            w1 = fmaf(l1, atv[j], w1);
        }
        w0 += __shfl_xor(w0, 1, 64);  w1 += __shfl_xor(w1, 1, 64);
        w0 += __shfl_xor(w0, 2, 64);  w1 += __shfl_xor(w1, 2, 64);
        w0 += __shfl_xor(w0, 4, 64);  w1 += __shfl_xor(w1, 4, 64);
        float pe0 = (p + s < pend) ? __expf(w0) : 0.f;
        float pe1 = (p + 8 + s < pend) ? __expf(w1) : 0.f;
        ssum += pe0 + pe1;
        #pragma unroll
        for (int j = 0; j < 16; j++) {
            acc[j] = fmaf(pe0, xv0[j], acc[j]);
            acc[j] = fmaf(pe1, xv1[j], acc[j]);
        }
    }
    if (p < pend_pad) {   // one 8-edge tail
        const int off0 = csr_off[p + s];
        const char* rp0 = xlb + (unsigned int)(off0 + goff);
        uint4 va0 = *(const uint4*)rp0;
        uint4 vb0 = *(const uint4*)(rp0 + 16);
        f16v xv0;
        xv0[0]  = __uint_as_float(va0.x << 16); xv0[1]  = __uint_as_float(va0.x & 0xffff0000u);
        xv0[2]  = __uint_as_float(va0.y << 16); xv0[3]  = __uint_as_float(va0.y & 0xffff0000u);
        xv0[4]  = __uint_as_float(va0.z << 16); xv0[5]  = __uint_as_float(va0.z & 0xffff0000u);
        xv0[6]  = __uint_as_float(va0.w << 16); xv0[7]  = __uint_as_float(va0.w & 0xffff0000u);
        xv0[8]  = __uint_as_float(vb0.x << 16); xv0[9]  = __uint_as_float(vb0.x & 0xffff0000u);
        xv0[10] = __uint_as_float(vb0.y << 16); xv0[11] = __uint_as_float(vb0.y & 0xffff0000u);
        xv0[12] = __uint_as_float(vb0.z << 16); xv0[13] = __uint_as_float(vb0.z & 0xffff0000u);
        xv0[14] = __uint_as_float(vb0.w << 16); xv0[15] = __uint_as_float(vb0.w & 0xffff0000u);
        float w0 = 0.f;
        #pragma unroll
        for (int j = 0; j < 16; j++) {
            float z0 = xv0[j] + xrv[j];
            float l0 = fmaxf(z0, NEG * z0);
            w0 = fmaf(l0, atv[j], w0);
        }
        w0 += __shfl_xor(w0, 1, 64);
        w0 += __shfl_xor(w0, 2, 64);
        w0 += __shfl_xor(w0, 4, 64);
        float pe0 = (p + s < pend) ? __expf(w0) : 0.f;
        ssum += pe0;
        #pragma unroll
        for (int j = 0; j < 16; j++) acc[j] = fmaf(pe0, xv0[j], acc[j]);
    }

    // reduce over the 8 slots
    ssum += __shfl_xor(ssum, 8, 64);
    ssum += __shfl_xor(ssum, 16, 64);
    ssum += __shfl_xor(ssum, 32, 64);
    #pragma unroll
    for (int j = 0; j < 16; j++) {
        acc[j] += __shfl_xor(acc[j], 8, 64);
        acc[j] += __shfl_xor(acc[j], 16, 64);
        acc[j] += __shfl_xor(acc[j], 32, 64);
    }
    const float inv = (ssum > 0.f) ? 1.f / ssum : 0.f;

    // pair-select (2s, 2s+1) via cndmask tree (scalar SSA temps)
    float a0 = (s & 1) ? acc[2]  : acc[0];
    float a1 = (s & 1) ? acc[6]  : acc[4];
    float a2 = (s & 1) ? acc[10] : acc[8];
    float a3 = (s & 1) ? acc[14] : acc[12];
    float b0 = (s & 2) ? a1 : a0;
    float b1 = (s & 2) ? a3 : a2;
    const float E0 = (s & 4) ? b1 : b0;
    float c0 = (s & 1) ? acc[3]  : acc[1];
    float c1 = (s & 1) ? acc[7]  : acc[5];
    float c2 = (s & 1) ? acc[11] : acc[9];
    float c3 = (s & 1) ? acc[15] : acc[13];
    float e0 = (s & 2) ? c1 : c0;
    float e1 = (s & 2) ? c3 : c2;
    const float E1 = (s & 4) ? e1 : e0;

    // 8x8 transpose shuffle -> lane l holds dims (2l, 2l+1); linear store
    const int srcl = ((lane & 7) << 3) | (lane >> 3);
    const float F0 = __shfl(E0, srcl, 64);
    const float F1 = __shfl(E1, srcl, 64);

    const float2 bv = *(const float2*)&bias[2 * lane];
    const float o0 = fmaxf(fmaf(F0, inv, bv.x), 0.f);
    const float o1 = fmaxf(fmaf(F1, inv, bv.y), 0.f);
    *(float2*)&xout[(size_t)n * DH + 2 * lane] = make_float2(o0, o1);
}

// ---------------- host launch ----------------

static inline size_t align256(size_t x) { return (x + 255) & ~(size_t)255; }

extern "C" void kernel_launch(void* const* d_in, const int* in_sizes, int n_in,
                              void* d_out, int out_size, void* d_ws, size_t ws_size,
                              hipStream_t stream) {
    (void)in_sizes; (void)n_in; (void)out_size; (void)ws_size;

    const float* x   = (const float*)d_in[0];
    const int* ei    = (const int*)d_in[1];
    const float* Wl  = (const float*)d_in[2];
    const float* bl  = (const float*)d_in[3];
    const float* Wr  = (const float*)d_in[4];
    const float* br  = (const float*)d_in[5];
    const float* att = (const float*)d_in[6];
    const float* bias= (const float*)d_in[7];
    const float* W1  = (const float*)d_in[8];
    const float* b1  = (const float*)d_in[9];
    const float* W2  = (const float*)d_in[10];
    const float* b2  = (const float*)d_in[11];
    float* out = (float*)d_out;

    const int* src = ei;
    const int* dst = ei + EE;

    const size_t EP = (size_t)EE + 8 * (size_t)NN;  // padded csr capacity

    char* w = (char*)d_ws;
    float* xA  = (float*)w; w += align256((size_t)NN * DH * 4);
    float* xB  = (float*)w; w += align256((size_t)NN * DH * 4);
    unsigned int* xl16 = (unsigned int*)w; w += align256((size_t)NN * DH * 2);
    float* xrb = (float*)w; w += align256((size_t)NN * DH * 4);
    float* hbuf = (float*)w; w += align256((size_t)NN * DH * 4);
    uint2* pairs = (uint2*)w; w += align256((size_t)EE * 8);
    int* csr_off = (int*)w; w += align256(EP * 4);
    int* prow    = (int*)w; w += align256((size_t)(NN + 1) * 4);
    int* deg     = (int*)w; w += align256((size_t)NN * 4);
    int* cursor  = (int*)w; w += align256((size_t)NN * 4);
    int* bucket_hist   = (int*)w; w += align256(NBK * 4);
    int* bucket_cursor = (int*)w; w += align256(NBK * 4);
    int* bsums   = (int*)w; w += align256(256 * 4);

    const int nb_scan = (NN + 255) / 256;     // 196
    const int nb_edge = (EE + 255) / 256;     // 6250
    const int nb_chunk = (EE + CHUNK - 1) / CHUNK;  // 391
    const int nb_gemm = (NN + 127) / 128;     // 391
    const int nb_node = (NN + 3) / 4;         // 12500

    // ---- build bucketed CSR (by dst, rows padded to 8, byte offsets) ----
    hipMemsetAsync(deg, 0, (size_t)NN * 4, stream);
    hipMemsetAsync(cursor, 0, (size_t)NN * 4, stream);
    hipMemsetAsync(bucket_hist, 0, NBK * 4, stream);
    k_hist<<<nb_chunk, 256, 0, stream>>>(dst, deg, bucket_hist);
    k_scan_bucket<<<1, NBK, 0, stream>>>(bucket_hist, bucket_cursor);
    k_scatter<<<nb_chunk, 256, 0, stream>>>(src, dst, bucket_cursor, pairs);
    k_scan_block<<<nb_scan, 256, 0, stream>>>(deg, prow, bsums, NN);
    k_scan_aux<<<1, 256, 0, stream>>>(bsums, nb_scan);
    k_scan_add<<<nb_scan, 256, 0, stream>>>(prow, bsums, NN);
    k_fill2<<<nb_edge, 256, 0, stream>>>(pairs, prow, cursor, csr_off);
    k_pad<<<nb_scan, 256, 0, stream>>>(deg, prow, csr_off);

    // ---- 3 GATv2 layers ----
    const float* xin = x;
    for (int l = 0; l < 3; ++l) {
        const float* Wl_l = Wl + (size_t)l * DH * DH;
        const float* Wr_l = Wr + (size_t)l * DH * DH;
        const float* bl_l = bl + (size_t)l * DH;
        const float* br_l = br + (size_t)l * DH;
        const float* att_l = att + (size_t)l * DH;
        const float* bias_l = bias + (size_t)l * DH;
        float* xo = (l & 1) ? xB : xA;

        k_mfma<DH><<<dim3(nb_gemm, 2), 256, 0, stream>>>(xin, Wl_l, bl_l, xl16,
                                                         Wr_l, br_l, xrb, NN);
        k_gat_node<<<nb_node, 256, 0, stream>>>((const unsigned short*)xl16, xrb,
                                                att_l, bias_l, csr_off, prow, deg, xo);
        xin = xo;
    }

    // ---- head MLP (fp32 out; A-stage converts fp32->bf16 on the fly) ----
    k_mfma<DH><<<dim3(nb_gemm, 1), 256, 0, stream>>>(xin, W1, b1, nullptr,
                                                     nullptr, nullptr, hbuf, NN);
    k_mfma<DOUT><<<dim3(nb_gemm, 1), 256, 0, stream>>>(hbuf, W2, b2, nullptr,
                                                       nullptr, nullptr, out, NN);
}

// Round 8
// 504.540 us; speedup vs baseline: 1.4327x; 1.2225x over previous
//
#include <hip/hip_runtime.h>
#include <hip/hip_bf16.h>

#define NN 50000
#define EE 1600000
#define DH 128
#define DOUT 64
#define NEG 0.2f
#define NBK 256            // bucket array size (used: (NN+255)>>8 = 196)
#define CHUNK 4096         // edges per scatter block

typedef short bf16x8 __attribute__((ext_vector_type(8)));
typedef float f32x4 __attribute__((ext_vector_type(4)));

// ---------------- CSR build (bucketed) ----------------

__global__ __launch_bounds__(256) void k_hist(const int* __restrict__ dst,
                                              int* __restrict__ deg,
                                              int* __restrict__ bucket_hist) {
    __shared__ int lh[NBK];
    lh[threadIdx.x] = 0;
    __syncthreads();
    const int e0 = blockIdx.x * CHUNK;
    #pragma unroll
    for (int k = 0; k < CHUNK / 256; k++) {
        int e = e0 + k * 256 + threadIdx.x;
        if (e < EE) {
            int d = dst[e];
            atomicAdd(&deg[d], 1);
            atomicAdd(&lh[((unsigned)d) >> 8], 1);
        }
    }
    __syncthreads();
    int c = lh[threadIdx.x];
    if (c) atomicAdd(&bucket_hist[threadIdx.x], c);
}

__global__ __launch_bounds__(256) void k_scan_bucket(const int* __restrict__ bucket_hist,
                                                     int* __restrict__ bucket_cursor) {
    __shared__ int tmp[NBK];
    int t = threadIdx.x;
    int v = bucket_hist[t];
    tmp[t] = v;
    __syncthreads();
    #pragma unroll
    for (int off = 1; off < NBK; off <<= 1) {
        int tt = (t >= off) ? tmp[t - off] : 0;
        __syncthreads();
        tmp[t] += tt;
        __syncthreads();
    }
    bucket_cursor[t] = tmp[t] - v;
}

__global__ __launch_bounds__(256) void k_scatter(const int* __restrict__ src,
                                                 const int* __restrict__ dst,
                                                 int* __restrict__ bucket_cursor,
                                                 uint2* __restrict__ pairs) {
    __shared__ int lh[NBK];
    __shared__ int lbase[NBK];
    lh[threadIdx.x] = 0;
    __syncthreads();
    const int e0 = blockIdx.x * CHUNK;
    int dl[CHUNK / 256];
    #pragma unroll
    for (int k = 0; k < CHUNK / 256; k++) {
        int e = e0 + k * 256 + threadIdx.x;
        dl[k] = (e < EE) ? dst[e] : -1;
        if (dl[k] >= 0) atomicAdd(&lh[((unsigned)dl[k]) >> 8], 1);
    }
    __syncthreads();
    int c = lh[threadIdx.x];
    lbase[threadIdx.x] = c ? atomicAdd(&bucket_cursor[threadIdx.x], c) : 0;
    __syncthreads();
    lh[threadIdx.x] = 0;   // reuse as local running cursor
    __syncthreads();
    #pragma unroll
    for (int k = 0; k < CHUNK / 256; k++) {
        int e = e0 + k * 256 + threadIdx.x;
        if (dl[k] >= 0) {
            int b = ((unsigned)dl[k]) >> 8;
            int loc = atomicAdd(&lh[b], 1);
            pairs[lbase[b] + loc] = make_uint2((unsigned)src[e], (unsigned)dl[k]);
        }
    }
}

__global__ __launch_bounds__(256) void k_scan_block(const int* __restrict__ deg,
                                                    int* __restrict__ out,
                                                    int* __restrict__ bsums, int n) {
    __shared__ int tmp[256];
    int i = blockIdx.x * 256 + threadIdx.x;
    int v = (i < n) ? ((deg[i] + 7) & ~7) : 0;
    tmp[threadIdx.x] = v;
    __syncthreads();
    #pragma unroll
    for (int off = 1; off < 256; off <<= 1) {
        int t = (threadIdx.x >= off) ? tmp[threadIdx.x - off] : 0;
        __syncthreads();
        tmp[threadIdx.x] += t;
        __syncthreads();
    }
    if (i < n) out[i] = tmp[threadIdx.x] - v;
    if (threadIdx.x == 255) bsums[blockIdx.x] = tmp[255];
}

__global__ __launch_bounds__(256) void k_scan_aux(int* __restrict__ bsums, int nb) {
    __shared__ int tmp[256];
    int t = threadIdx.x;
    int v = (t < nb) ? bsums[t] : 0;
    tmp[t] = v;
    __syncthreads();
    #pragma unroll
    for (int off = 1; off < 256; off <<= 1) {
        int tt = (t >= off) ? tmp[t - off] : 0;
        __syncthreads();
        tmp[t] += tt;
        __syncthreads();
    }
    if (t < nb) bsums[t] = tmp[t] - v;
}

__global__ __launch_bounds__(256) void k_scan_add(int* __restrict__ out,
                                                  const int* __restrict__ bsums, int n) {
    int i = blockIdx.x * 256 + threadIdx.x;
    if (i < n) out[i] += bsums[blockIdx.x];
}

// final fill: pairs (bucket-ordered) -> csr at padded row positions.
// stores PRE-MULTIPLIED byte offset (src * 256) of the bf16 feature row.
__global__ __launch_bounds__(256) void k_fill2(const uint2* __restrict__ pairs,
                                               const int* __restrict__ prow,
                                               int* __restrict__ cursor,
                                               int* __restrict__ csr_off) {
    int e = blockIdx.x * 256 + threadIdx.x;
    if (e < EE) {
        uint2 pr = pairs[e];
        int d = (int)pr.y;
        int pos = prow[d] + atomicAdd(&cursor[d], 1);
        csr_off[pos] = (int)(pr.x << 8);
    }
}

// pad slots -> offset 0 (node 0's row; logit killed in gat kernel)
__global__ __launch_bounds__(256) void k_pad(const int* __restrict__ deg,
                                             const int* __restrict__ prow,
                                             int* __restrict__ csr_off) {
    int n = blockIdx.x * 256 + threadIdx.x;
    if (n < NN) {
        int d = deg[n];
        int p = prow[n] + d;
        int e = prow[n] + ((d + 7) & ~7);
        for (; p < e; ++p) csr_off[p] = 0;
    }
}

// ---------------- helpers ----------------

static __device__ __forceinline__ unsigned int f2bf(float f) {
    unsigned int u = __float_as_uint(f);
    return (u + 0x7fffu + ((u >> 16) & 1u)) >> 16;  // RNE
}
static __device__ __forceinline__ unsigned int pack2bf(float lo, float hi) {
    return f2bf(lo) | (f2bf(hi) << 16);
}

// ---------------- MFMA GEMM: C[n,m] = sum_k X[n,k]*W[m,k] + b[m] ----------------
// K = 128, A = X rows (fp32 -> bf16 on stage), B = W rows (fp32 -> bf16).
// LDS layout [kc][kg][row][8]: fragment ds_read_b128 is contiguous per
// 16-lane group (conflict-free). 256 threads = 4 waves.

template <int BN>
__global__ __launch_bounds__(256) void k_mfma(const float* __restrict__ X,
                                              const float* __restrict__ W0,
                                              const float* __restrict__ b0,
                                              unsigned int* __restrict__ C0bf,
                                              const float* __restrict__ W1,
                                              const float* __restrict__ b1,
                                              float* __restrict__ C1,
                                              int nrows) {
    constexpr int MF = (BN == 128) ? 4 : 2;   // m-fragments per wave
    constexpr int NF = 4;                     // n-fragments per wave
    __shared__ __align__(16) unsigned short As[4][4][128][8];
    __shared__ __align__(16) unsigned short Bs[4][4][BN][8];

    const int tid = threadIdx.x;
    const int row0 = blockIdx.x * 128;
    const bool bfout = (blockIdx.y == 0) && (C0bf != nullptr);
    const float* W = (blockIdx.y == 0) ? W0 : W1;
    const float* bias = (blockIdx.y == 0) ? b0 : b1;

    // stage A: 128 rows x 128 cols fp32 -> bf16
    #pragma unroll
    for (int i = 0; i < 16; i++) {
        int L = i * 256 + tid;          // 0..4095
        int r = L >> 5, kq = L & 31;    // kq*4 = k
        int gr = row0 + r;
        float4 v = make_float4(0.f, 0.f, 0.f, 0.f);
        if (gr < nrows) v = *(const float4*)&X[(size_t)gr * 128 + kq * 4];
        int k = kq * 4;
        int kc = k >> 5, kg = (k >> 3) & 3, e = k & 7;
        *(uint2*)&As[kc][kg][r][e] = make_uint2(pack2bf(v.x, v.y), pack2bf(v.z, v.w));
    }
    // stage B: BN rows x 128 cols fp32 -> bf16
    #pragma unroll
    for (int i = 0; i < (BN * 32) / 256; i++) {
        int L = i * 256 + tid;
        int r = L >> 5, kq = L & 31;
        float4 v = *(const float4*)&W[(size_t)r * 128 + kq * 4];
        int k = kq * 4;
        int kc = k >> 5, kg = (k >> 3) & 3, e = k & 7;
        *(uint2*)&Bs[kc][kg][r][e] = make_uint2(pack2bf(v.x, v.y), pack2bf(v.z, v.w));
    }
    __syncthreads();

    const int w = tid >> 6;
    const int lane = tid & 63;
    const int lr = lane & 15;
    const int kg = lane >> 4;
    const int rowbase = (BN == 128) ? (w >> 1) * 64 : w * 32;
    const int colbase = (BN == 128) ? (w & 1) * 64 : 0;

    f32x4 acc[MF][NF];
    #pragma unroll
    for (int i = 0; i < MF; i++)
        #pragma unroll
        for (int j = 0; j < NF; j++) acc[i][j] = (f32x4){0.f, 0.f, 0.f, 0.f};

    #pragma unroll
    for (int kc = 0; kc < 4; kc++) {
        bf16x8 af[MF], bfr[NF];
        #pragma unroll
        for (int i = 0; i < MF; i++)
            af[i] = *(const bf16x8*)&As[kc][kg][rowbase + i * 16 + lr][0];
        #pragma unroll
        for (int j = 0; j < NF; j++)
            bfr[j] = *(const bf16x8*)&Bs[kc][kg][colbase + j * 16 + lr][0];
        #pragma unroll
        for (int i = 0; i < MF; i++)
            #pragma unroll
            for (int j = 0; j < NF; j++)
                acc[i][j] = __builtin_amdgcn_mfma_f32_16x16x32_bf16(af[i], bfr[j],
                                                                    acc[i][j], 0, 0, 0);
    }

    // epilogue: C/D layout col = lane&15, row = (lane>>4)*4 + reg
    #pragma unroll
    for (int i = 0; i < MF; i++) {
        #pragma unroll
        for (int reg = 0; reg < 4; reg++) {
            int row = rowbase + i * 16 + (lane >> 4) * 4 + reg;
            int gr = row0 + row;
            if (gr < nrows) {
                #pragma unroll
                for (int j = 0; j < NF; j++) {
                    int col = colbase + j * 16 + lr;
                    float v = acc[i][j][reg] + bias[col];
                    if (bfout) {
                        float vn = __shfl_xor(v, 1, 64);
                        if (!(lane & 1)) {
                            C0bf[(size_t)gr * (BN / 2) + (col >> 1)] = pack2bf(v, vn);
                        }
                    } else {
                        C1[(size_t)gr * BN + col] = v;
                    }
                }
            }
        }
    }
}

// ---------------- fused per-node softmax + aggregate ----------------
// one wave per node; lane owns dims (2*lane, 2*lane+1). 8-edge batches:
// 8 independent dword gathers in flight (premultiplied byte offsets, aligned
// uint4 index loads). Logit: merge tree (7 static shfl) + butterfly 8/16/32
// -> lane holds edge (lane&7)'s full logit. No-max softmax (logits bounded).
// pe redistributed to all lanes via 7-static-shfl UNMERGE tree (no dynamic
// ds_bpermute). acc is lane-local (no epilogue reduce); ssum reduced once
// per node. All arrays static-indexed scalars (SSA; no alloca/LDS demotion).

__global__ __launch_bounds__(256) void k_gat_node(const unsigned short* __restrict__ xl16,
                                                  const float* __restrict__ xr,
                                                  const float* __restrict__ att,
                                                  const float* __restrict__ bias,
                                                  const int* __restrict__ csr_off,
                                                  const int* __restrict__ prow,
                                                  const int* __restrict__ deg,
                                                  float* __restrict__ xout) {
    const int lane = threadIdx.x & 63;
    const int n = blockIdx.x * 4 + (threadIdx.x >> 6);
    if (n >= NN) return;

    const int l7 = lane & 7;
    const float2 xrv = *(const float2*)&xr[(size_t)n * DH + 2 * lane];
    const float2 attv = *(const float2*)&att[2 * lane];
    const int p0 = prow[n];
    const int dg = deg[n];
    const int pend = p0 + dg;
    const int pend_pad = p0 + ((dg + 7) & ~7);

    float ssum_l = 0.f;           // per-lane sum of pe(slot=l7) over batches
    float ax = 0.f, ay = 0.f;     // lane-local dim accumulators

    const char* xlb = (const char*)xl16;
    const unsigned int lb = (unsigned int)lane * 4u;   // dword offset within row

    for (int p = p0; p < pend_pad; p += 8) {
        uint4 ia = *(const uint4*)&csr_off[p];
        uint4 ib = *(const uint4*)&csr_off[p + 4];
        unsigned int u0 = *(const unsigned int*)(xlb + (ia.x + lb));
        unsigned int u1 = *(const unsigned int*)(xlb + (ia.y + lb));
        unsigned int u2 = *(const unsigned int*)(xlb + (ia.z + lb));
        unsigned int u3 = *(const unsigned int*)(xlb + (ia.w + lb));
        unsigned int u4 = *(const unsigned int*)(xlb + (ib.x + lb));
        unsigned int u5 = *(const unsigned int*)(xlb + (ib.y + lb));
        unsigned int u6 = *(const unsigned int*)(xlb + (ib.z + lb));
        unsigned int u7 = *(const unsigned int*)(xlb + (ib.w + lb));
        unsigned int uu[8] = {u0, u1, u2, u3, u4, u5, u6, u7};

        float x0[8], x1[8], w[8];
        #pragma unroll
        for (int j = 0; j < 8; j++) {
            x0[j] = __uint_as_float(uu[j] << 16);
            x1[j] = __uint_as_float(uu[j] & 0xffff0000u);
            float z0 = x0[j] + xrv.x;
            float z1 = x1[j] + xrv.y;
            float l0 = fmaxf(z0, NEG * z0);
            float l1 = fmaxf(z1, NEG * z1);
            w[j] = fmaf(l0, attv.x, l1 * attv.y);
        }

        // merge tree: lane ends with w[l7] summed over its 8-lane dim group
        float v4[4], v2[2], S;
        {
            const bool hi = (lane & 1);
            #pragma unroll
            for (int i = 0; i < 4; i++) {
                float keep = hi ? w[2 * i + 1] : w[2 * i];
                float send = hi ? w[2 * i] : w[2 * i + 1];
                v4[i] = keep + __shfl_xor(send, 1, 64);
            }
        }
        {
            const bool hi = (lane & 2);
            #pragma unroll
            for (int i = 0; i < 2; i++) {
                float keep = hi ? v4[2 * i + 1] : v4[2 * i];
                float send = hi ? v4[2 * i] : v4[2 * i + 1];
                v2[i] = keep + __shfl_xor(send, 2, 64);
            }
        }
        {
            const bool hi = (lane & 4);
            float keep = hi ? v2[1] : v2[0];
            float send = hi ? v2[0] : v2[1];
            S = keep + __shfl_xor(send, 4, 64);
        }
        // butterfly across the eight 8-lane groups -> full 128-dim logit
        S += __shfl_xor(S, 8, 64);
        S += __shfl_xor(S, 16, 64);
        S += __shfl_xor(S, 32, 64);

        // no-max softmax; kill padded edges
        float pe = (p + l7 < pend) ? __expf(S) : 0.f;
        ssum_l += pe;

        // unmerge tree: expand pe -> pe[0..7] on every lane (7 static shfls)
        float q = __shfl_xor(pe, 1, 64);
        float pA = (l7 & 1) ? q : pe;    // slot (l7 & ~1)
        float pB = (l7 & 1) ? pe : q;    // slot (l7 | 1)
        float qA = __shfl_xor(pA, 2, 64);
        float qB = __shfl_xor(pB, 2, 64);
        float p00 = (l7 & 2) ? qA : pA;  // slot bits {b1=0,b0=0}
        float p01 = (l7 & 2) ? qB : pB;
        float p10 = (l7 & 2) ? pA : qA;
        float p11 = (l7 & 2) ? pB : qB;
        float r00 = __shfl_xor(p00, 4, 64);
        float r01 = __shfl_xor(p01, 4, 64);
        float r10 = __shfl_xor(p10, 4, 64);
        float r11 = __shfl_xor(p11, 4, 64);
        float pe0 = (l7 & 4) ? r00 : p00;
        float pe1 = (l7 & 4) ? r01 : p01;
        float pe2 = (l7 & 4) ? r10 : p10;
        float pe3 = (l7 & 4) ? r11 : p11;
        float pe4 = (l7 & 4) ? p00 : r00;
        float pe5 = (l7 & 4) ? p01 : r01;
        float pe6 = (l7 & 4) ? p10 : r10;
        float pe7 = (l7 & 4) ? p11 : r11;

        ax = fmaf(pe0, x0[0], ax);  ay = fmaf(pe0, x1[0], ay);
        ax = fmaf(pe1, x0[1], ax);  ay = fmaf(pe1, x1[1], ay);
        ax = fmaf(pe2, x0[2], ax);  ay = fmaf(pe2, x1[2], ay);
        ax = fmaf(pe3, x0[3], ax);  ay = fmaf(pe3, x1[3], ay);
        ax = fmaf(pe4, x0[4], ax);  ay = fmaf(pe4, x1[4], ay);
        ax = fmaf(pe5, x0[5], ax);  ay = fmaf(pe5, x1[5], ay);
        ax = fmaf(pe6, x0[6], ax);  ay = fmaf(pe6, x1[6], ay);
        ax = fmaf(pe7, x0[7], ax);  ay = fmaf(pe7, x1[7], ay);
    }

    // total denom: ssum_l holds slot l7's sum (group-uniform); reduce 8 slots
    float st = ssum_l;
    st += __shfl_xor(st, 1, 64);
    st += __shfl_xor(st, 2, 64);
    st += __shfl_xor(st, 4, 64);
    const float inv = (st > 0.f) ? 1.f / st : 0.f;

    const float2 bv = *(const float2*)&bias[2 * lane];
    const float o0 = fmaxf(fmaf(ax, inv, bv.x), 0.f);
    const float o1 = fmaxf(fmaf(ay, inv, bv.y), 0.f);
    *(float2*)&xout[(size_t)n * DH + 2 * lane] = make_float2(o0, o1);
}

// ---------------- host launch ----------------

static inline size_t align256(size_t x) { return (x + 255) & ~(size_t)255; }

extern "C" void kernel_launch(void* const* d_in, const int* in_sizes, int n_in,
                              void* d_out, int out_size, void* d_ws, size_t ws_size,
                              hipStream_t stream) {
    (void)in_sizes; (void)n_in; (void)out_size; (void)ws_size;

    const float* x   = (const float*)d_in[0];
    const int* ei    = (const int*)d_in[1];
    const float* Wl  = (const float*)d_in[2];
    const float* bl  = (const float*)d_in[3];
    const float* Wr  = (const float*)d_in[4];
    const float* br  = (const float*)d_in[5];
    const float* att = (const float*)d_in[6];
    const float* bias= (const float*)d_in[7];
    const float* W1  = (const float*)d_in[8];
    const float* b1  = (const float*)d_in[9];
    const float* W2  = (const float*)d_in[10];
    const float* b2  = (const float*)d_in[11];
    float* out = (float*)d_out;

    const int* src = ei;
    const int* dst = ei + EE;

    const size_t EP = (size_t)EE + 8 * (size_t)NN;  // padded csr capacity

    char* w = (char*)d_ws;
    float* xA  = (float*)w; w += align256((size_t)NN * DH * 4);
    float* xB  = (float*)w; w += align256((size_t)NN * DH * 4);
    unsigned int* xl16 = (unsigned int*)w; w += align256((size_t)NN * DH * 2);
    float* xrb = (float*)w; w += align256((size_t)NN * DH * 4);
    float* hbuf = (float*)w; w += align256((size_t)NN * DH * 4);
    uint2* pairs = (uint2*)w; w += align256((size_t)EE * 8);
    int* csr_off = (int*)w; w += align256(EP * 4);
    int* prow    = (int*)w; w += align256((size_t)(NN + 1) * 4);
    int* deg     = (int*)w; w += align256((size_t)NN * 4);
    int* cursor  = (int*)w; w += align256((size_t)NN * 4);
    int* bucket_hist   = (int*)w; w += align256(NBK * 4);
    int* bucket_cursor = (int*)w; w += align256(NBK * 4);
    int* bsums   = (int*)w; w += align256(256 * 4);

    const int nb_scan = (NN + 255) / 256;     // 196
    const int nb_edge = (EE + 255) / 256;     // 6250
    const int nb_chunk = (EE + CHUNK - 1) / CHUNK;  // 391
    const int nb_gemm = (NN + 127) / 128;     // 391
    const int nb_node = (NN + 3) / 4;         // 12500

    // ---- build bucketed CSR (by dst, rows padded to 8, byte offsets) ----
    hipMemsetAsync(deg, 0, (size_t)NN * 4, stream);
    hipMemsetAsync(cursor, 0, (size_t)NN * 4, stream);
    hipMemsetAsync(bucket_hist, 0, NBK * 4, stream);
    k_hist<<<nb_chunk, 256, 0, stream>>>(dst, deg, bucket_hist);
    k_scan_bucket<<<1, NBK, 0, stream>>>(bucket_hist, bucket_cursor);
    k_scatter<<<nb_chunk, 256, 0, stream>>>(src, dst, bucket_cursor, pairs);
    k_scan_block<<<nb_scan, 256, 0, stream>>>(deg, prow, bsums, NN);
    k_scan_aux<<<1, 256, 0, stream>>>(bsums, nb_scan);
    k_scan_add<<<nb_scan, 256, 0, stream>>>(prow, bsums, NN);
    k_fill2<<<nb_edge, 256, 0, stream>>>(pairs, prow, cursor, csr_off);
    k_pad<<<nb_scan, 256, 0, stream>>>(deg, prow, csr_off);

    // ---- 3 GATv2 layers ----
    const float* xin = x;
    for (int l = 0; l < 3; ++l) {
        const float* Wl_l = Wl + (size_t)l * DH * DH;
        const float* Wr_l = Wr + (size_t)l * DH * DH;
        const float* bl_l = bl + (size_t)l * DH;
        const float* br_l = br + (size_t)l * DH;
        const float* att_l = att + (size_t)l * DH;
        const float* bias_l = bias + (size_t)l * DH;
        float* xo = (l & 1) ? xB : xA;

        k_mfma<DH><<<dim3(nb_gemm, 2), 256, 0, stream>>>(xin, Wl_l, bl_l, xl16,
                                                         Wr_l, br_l, xrb, NN);
        k_gat_node<<<nb_node, 256, 0, stream>>>((const unsigned short*)xl16, xrb,
                                                att_l, bias_l, csr_off, prow, deg, xo);
        xin = xo;
    }

    // ---- head MLP (fp32 out; A-stage converts fp32->bf16 on the fly) ----
    k_mfma<DH><<<dim3(nb_gemm, 1), 256, 0, stream>>>(xin, W1, b1, nullptr,
                                                     nullptr, nullptr, hbuf, NN);
    k_mfma<DOUT><<<dim3(nb_gemm, 1), 256, 0, stream>>>(hbuf, W2, b2, nullptr,
                                                       nullptr, nullptr, out, NN);
}

// Round 9
// 412.094 us; speedup vs baseline: 1.7541x; 1.2243x over previous
//
#include <hip/hip_runtime.h>
#include <hip/hip_bf16.h>

#define NN 50000
#define EE 1600000
#define DH 128
#define DOUT 64
#define NEG 0.2f
#define NBK 256            // bucket array size (used: (NN+255)>>8 = 196)
#define CHUNK 4096         // edges per scatter block

typedef short bf16x8 __attribute__((ext_vector_type(8)));
typedef float f32x4 __attribute__((ext_vector_type(4)));

// ---------------- CSR build (bucketed, no per-edge global atomics) ----------------

// bucket histogram of dst (LDS counters only)
__global__ __launch_bounds__(256) void k_bhist(const int* __restrict__ dst,
                                               int* __restrict__ bucket_hist) {
    __shared__ int lh[NBK];
    lh[threadIdx.x] = 0;
    __syncthreads();
    const int e0 = blockIdx.x * CHUNK;
    #pragma unroll
    for (int k = 0; k < CHUNK / 256; k++) {
        int e = e0 + k * 256 + threadIdx.x;
        if (e < EE) atomicAdd(&lh[((unsigned)dst[e]) >> 8], 1);
    }
    __syncthreads();
    int c = lh[threadIdx.x];
    if (c) atomicAdd(&bucket_hist[threadIdx.x], c);
}

// exclusive scan of bucket counts -> bucket_base (preserved) + bucket_cursor
__global__ __launch_bounds__(256) void k_scan_bucket(const int* __restrict__ bucket_hist,
                                                     int* __restrict__ bucket_base,
                                                     int* __restrict__ bucket_cursor) {
    __shared__ int tmp[NBK];
    int t = threadIdx.x;
    int v = bucket_hist[t];
    tmp[t] = v;
    __syncthreads();
    #pragma unroll
    for (int off = 1; off < NBK; off <<= 1) {
        int tt = (t >= off) ? tmp[t - off] : 0;
        __syncthreads();
        tmp[t] += tt;
        __syncthreads();
    }
    bucket_base[t] = tmp[t] - v;
    bucket_cursor[t] = tmp[t] - v;
}

// scatter (src,dst) pairs into bucket-contiguous regions
__global__ __launch_bounds__(256) void k_scatter(const int* __restrict__ src,
                                                 const int* __restrict__ dst,
                                                 int* __restrict__ bucket_cursor,
                                                 uint2* __restrict__ pairs) {
    __shared__ int lh[NBK];
    __shared__ int lbase[NBK];
    lh[threadIdx.x] = 0;
    __syncthreads();
    const int e0 = blockIdx.x * CHUNK;
    int dl[CHUNK / 256];
    #pragma unroll
    for (int k = 0; k < CHUNK / 256; k++) {
        int e = e0 + k * 256 + threadIdx.x;
        dl[k] = (e < EE) ? dst[e] : -1;
        if (dl[k] >= 0) atomicAdd(&lh[((unsigned)dl[k]) >> 8], 1);
    }
    __syncthreads();
    int c = lh[threadIdx.x];
    lbase[threadIdx.x] = c ? atomicAdd(&bucket_cursor[threadIdx.x], c) : 0;
    __syncthreads();
    lh[threadIdx.x] = 0;   // reuse as local running cursor
    __syncthreads();
    #pragma unroll
    for (int k = 0; k < CHUNK / 256; k++) {
        int e = e0 + k * 256 + threadIdx.x;
        if (dl[k] >= 0) {
            int b = ((unsigned)dl[k]) >> 8;
            int loc = atomicAdd(&lh[b], 1);
            pairs[lbase[b] + loc] = make_uint2((unsigned)src[e], (unsigned)dl[k]);
        }
    }
}

// per-bucket: LDS histogram + padded scan + fill + pad; writes deg/prow/csr.
// bucket b owns nodes [b*256, b*256+256); csr region base = bucket_base[b] + b*2048
// (2048 >= 256 nodes * 7 max pad slack). Zero global atomics.
__global__ __launch_bounds__(256) void k_bucket(const uint2* __restrict__ pairs,
                                                const int* __restrict__ bucket_base,
                                                const int* __restrict__ bucket_hist,
                                                int* __restrict__ csr_off,
                                                int* __restrict__ prow,
                                                int* __restrict__ deg) {
    __shared__ int cnt[256];
    __shared__ int sbase[256];
    __shared__ int scn[256];
    __shared__ int cur[256];
    const int b = blockIdx.x;
    const int t = threadIdx.x;
    const int pstart = bucket_base[b];
    const int pcnt = bucket_hist[b];

    cnt[t] = 0;
    cur[t] = 0;
    __syncthreads();
    for (int i = t; i < pcnt; i += 256)
        atomicAdd(&cnt[pairs[pstart + i].y & 255u], 1);
    __syncthreads();

    const int d = cnt[t];
    const int padded = (d + 7) & ~7;
    scn[t] = padded;
    __syncthreads();
    #pragma unroll
    for (int off = 1; off < 256; off <<= 1) {
        int v = (t >= off) ? scn[t - off] : 0;
        __syncthreads();
        scn[t] += v;
        __syncthreads();
    }
    const int mybase = scn[t] - padded;   // exclusive scan (bucket-relative)
    sbase[t] = mybase;
    const int cb = pstart + b * 2048;     // csr region base for this bucket
    const int node = b * 256 + t;
    if (node < NN) {
        prow[node] = cb + mybase;
        deg[node] = d;
    }
    __syncthreads();

    for (int i = t; i < pcnt; i += 256) {
        uint2 pr = pairs[pstart + i];
        int ln = (int)(pr.y & 255u);
        int pos = atomicAdd(&cur[ln], 1);
        csr_off[cb + sbase[ln] + pos] = (int)(pr.x << 8);
    }
    __syncthreads();

    for (int p = d; p < padded; p++) csr_off[cb + mybase + p] = 0;
}

// ---------------- helpers ----------------

static __device__ __forceinline__ unsigned int f2bf(float f) {
    unsigned int u = __float_as_uint(f);
    return (u + 0x7fffu + ((u >> 16) & 1u)) >> 16;  // RNE
}
static __device__ __forceinline__ unsigned int pack2bf(float lo, float hi) {
    return f2bf(lo) | (f2bf(hi) << 16);
}

// ---------------- MFMA GEMM: C[n,m] = sum_k X[n,k]*W[m,k] + b[m] ----------------
// K = 128, A = X rows (fp32 -> bf16 on stage), B = W rows (fp32 -> bf16).
// LDS layout [kc][kg][row][8]: fragment ds_read_b128 is contiguous per
// 16-lane group (conflict-free). 256 threads = 4 waves.

template <int BN>
__global__ __launch_bounds__(256) void k_mfma(const float* __restrict__ X,
                                              const float* __restrict__ W0,
                                              const float* __restrict__ b0,
                                              unsigned int* __restrict__ C0bf,
                                              const float* __restrict__ W1,
                                              const float* __restrict__ b1,
                                              float* __restrict__ C1,
                                              int nrows) {
    constexpr int MF = (BN == 128) ? 4 : 2;   // m-fragments per wave
    constexpr int NF = 4;                     // n-fragments per wave
    __shared__ __align__(16) unsigned short As[4][4][128][8];
    __shared__ __align__(16) unsigned short Bs[4][4][BN][8];

    const int tid = threadIdx.x;
    const int row0 = blockIdx.x * 128;
    const bool bfout = (blockIdx.y == 0) && (C0bf != nullptr);
    const float* W = (blockIdx.y == 0) ? W0 : W1;
    const float* bias = (blockIdx.y == 0) ? b0 : b1;

    // stage A: 128 rows x 128 cols fp32 -> bf16
    #pragma unroll
    for (int i = 0; i < 16; i++) {
        int L = i * 256 + tid;          // 0..4095
        int r = L >> 5, kq = L & 31;    // kq*4 = k
        int gr = row0 + r;
        float4 v = make_float4(0.f, 0.f, 0.f, 0.f);
        if (gr < nrows) v = *(const float4*)&X[(size_t)gr * 128 + kq * 4];
        int k = kq * 4;
        int kc = k >> 5, kg = (k >> 3) & 3, e = k & 7;
        *(uint2*)&As[kc][kg][r][e] = make_uint2(pack2bf(v.x, v.y), pack2bf(v.z, v.w));
    }
    // stage B: BN rows x 128 cols fp32 -> bf16
    #pragma unroll
    for (int i = 0; i < (BN * 32) / 256; i++) {
        int L = i * 256 + tid;
        int r = L >> 5, kq = L & 31;
        float4 v = *(const float4*)&W[(size_t)r * 128 + kq * 4];
        int k = kq * 4;
        int kc = k >> 5, kg = (k >> 3) & 3, e = k & 7;
        *(uint2*)&Bs[kc][kg][r][e] = make_uint2(pack2bf(v.x, v.y), pack2bf(v.z, v.w));
    }
    __syncthreads();

    const int w = tid >> 6;
    const int lane = tid & 63;
    const int lr = lane & 15;
    const int kg = lane >> 4;
    const int rowbase = (BN == 128) ? (w >> 1) * 64 : w * 32;
    const int colbase = (BN == 128) ? (w & 1) * 64 : 0;

    f32x4 acc[MF][NF];
    #pragma unroll
    for (int i = 0; i < MF; i++)
        #pragma unroll
        for (int j = 0; j < NF; j++) acc[i][j] = (f32x4){0.f, 0.f, 0.f, 0.f};

    #pragma unroll
    for (int kc = 0; kc < 4; kc++) {
        bf16x8 af[MF], bfr[NF];
        #pragma unroll
        for (int i = 0; i < MF; i++)
            af[i] = *(const bf16x8*)&As[kc][kg][rowbase + i * 16 + lr][0];
        #pragma unroll
        for (int j = 0; j < NF; j++)
            bfr[j] = *(const bf16x8*)&Bs[kc][kg][colbase + j * 16 + lr][0];
        #pragma unroll
        for (int i = 0; i < MF; i++)
            #pragma unroll
            for (int j = 0; j < NF; j++)
                acc[i][j] = __builtin_amdgcn_mfma_f32_16x16x32_bf16(af[i], bfr[j],
                                                                    acc[i][j], 0, 0, 0);
    }

    // epilogue: C/D layout col = lane&15, row = (lane>>4)*4 + reg
    #pragma unroll
    for (int i = 0; i < MF; i++) {
        #pragma unroll
        for (int reg = 0; reg < 4; reg++) {
            int row = rowbase + i * 16 + (lane >> 4) * 4 + reg;
            int gr = row0 + row;
            if (gr < nrows) {
                #pragma unroll
                for (int j = 0; j < NF; j++) {
                    int col = colbase + j * 16 + lr;
                    float v = acc[i][j][reg] + bias[col];
                    if (bfout) {
                        float vn = __shfl_xor(v, 1, 64);
                        if (!(lane & 1)) {
                            C0bf[(size_t)gr * (BN / 2) + (col >> 1)] = pack2bf(v, vn);
                        }
                    } else {
                        C1[(size_t)gr * BN + col] = v;
                    }
                }
            }
        }
    }
}

// ---------------- fused per-node softmax + aggregate ----------------
// one wave per node; lane owns dims (2*lane, 2*lane+1). 8-edge batches:
// 8 independent dword gathers in flight (premultiplied byte offsets, aligned
// uint4 index loads). Logit: merge tree (7 static shfl) + butterfly 8/16/32
// -> lane holds edge (lane&7)'s full logit. No-max softmax (logits bounded).
// pe redistributed to all lanes via 7-static-shfl UNMERGE tree. acc is
// lane-local; ssum reduced once per node. All arrays static-indexed SSA.

__global__ __launch_bounds__(256) void k_gat_node(const unsigned short* __restrict__ xl16,
                                                  const float* __restrict__ xr,
                                                  const float* __restrict__ att,
                                                  const float* __restrict__ bias,
                                                  const int* __restrict__ csr_off,
                                                  const int* __restrict__ prow,
                                                  const int* __restrict__ deg,
                                                  float* __restrict__ xout) {
    const int lane = threadIdx.x & 63;
    const int n = blockIdx.x * 4 + (threadIdx.x >> 6);
    if (n >= NN) return;

    const int l7 = lane & 7;
    const float2 xrv = *(const float2*)&xr[(size_t)n * DH + 2 * lane];
    const float2 attv = *(const float2*)&att[2 * lane];
    const int p0 = prow[n];
    const int dg = deg[n];
    const int pend = p0 + dg;
    const int pend_pad = p0 + ((dg + 7) & ~7);

    float ssum_l = 0.f;           // per-lane sum of pe(slot=l7) over batches
    float ax = 0.f, ay = 0.f;     // lane-local dim accumulators

    const char* xlb = (const char*)xl16;
    const unsigned int lb = (unsigned int)lane * 4u;   // dword offset within row

    for (int p = p0; p < pend_pad; p += 8) {
        uint4 ia = *(const uint4*)&csr_off[p];
        uint4 ib = *(const uint4*)&csr_off[p + 4];
        unsigned int u0 = *(const unsigned int*)(xlb + (ia.x + lb));
        unsigned int u1 = *(const unsigned int*)(xlb + (ia.y + lb));
        unsigned int u2 = *(const unsigned int*)(xlb + (ia.z + lb));
        unsigned int u3 = *(const unsigned int*)(xlb + (ia.w + lb));
        unsigned int u4 = *(const unsigned int*)(xlb + (ib.x + lb));
        unsigned int u5 = *(const unsigned int*)(xlb + (ib.y + lb));
        unsigned int u6 = *(const unsigned int*)(xlb + (ib.z + lb));
        unsigned int u7 = *(const unsigned int*)(xlb + (ib.w + lb));
        unsigned int uu[8] = {u0, u1, u2, u3, u4, u5, u6, u7};

        float x0[8], x1[8], w[8];
        #pragma unroll
        for (int j = 0; j < 8; j++) {
            x0[j] = __uint_as_float(uu[j] << 16);
            x1[j] = __uint_as_float(uu[j] & 0xffff0000u);
            float z0 = x0[j] + xrv.x;
            float z1 = x1[j] + xrv.y;
            float l0 = fmaxf(z0, NEG * z0);
            float l1 = fmaxf(z1, NEG * z1);
            w[j] = fmaf(l0, attv.x, l1 * attv.y);
        }

        // merge tree: lane ends with w[l7] summed over its 8-lane dim group
        float v4[4], v2[2], S;
        {
            const bool hi = (lane & 1);
            #pragma unroll
            for (int i = 0; i < 4; i++) {
                float keep = hi ? w[2 * i + 1] : w[2 * i];
                float send = hi ? w[2 * i] : w[2 * i + 1];
                v4[i] = keep + __shfl_xor(send, 1, 64);
            }
        }
        {
            const bool hi = (lane & 2);
            #pragma unroll
            for (int i = 0; i < 2; i++) {
                float keep = hi ? v4[2 * i + 1] : v4[2 * i];
                float send = hi ? v4[2 * i] : v4[2 * i + 1];
                v2[i] = keep + __shfl_xor(send, 2, 64);
            }
        }
        {
            const bool hi = (lane & 4);
            float keep = hi ? v2[1] : v2[0];
            float send = hi ? v2[0] : v2[1];
            S = keep + __shfl_xor(send, 4, 64);
        }
        // butterfly across the eight 8-lane groups -> full 128-dim logit
        S += __shfl_xor(S, 8, 64);
        S += __shfl_xor(S, 16, 64);
        S += __shfl_xor(S, 32, 64);

        // no-max softmax; kill padded edges
        float pe = (p + l7 < pend) ? __expf(S) : 0.f;
        ssum_l += pe;

        // unmerge tree: expand pe -> pe[0..7] on every lane (7 static shfls)
        float q = __shfl_xor(pe, 1, 64);
        float pA = (l7 & 1) ? q : pe;    // slot (l7 & ~1)
        float pB = (l7 & 1) ? pe : q;    // slot (l7 | 1)
        float qA = __shfl_xor(pA, 2, 64);
        float qB = __shfl_xor(pB, 2, 64);
        float p00 = (l7 & 2) ? qA : pA;
        float p01 = (l7 & 2) ? qB : pB;
        float p10 = (l7 & 2) ? pA : qA;
        float p11 = (l7 & 2) ? pB : qB;
        float r00 = __shfl_xor(p00, 4, 64);
        float r01 = __shfl_xor(p01, 4, 64);
        float r10 = __shfl_xor(p10, 4, 64);
        float r11 = __shfl_xor(p11, 4, 64);
        float pe0 = (l7 & 4) ? r00 : p00;
        float pe1 = (l7 & 4) ? r01 : p01;
        float pe2 = (l7 & 4) ? r10 : p10;
        float pe3 = (l7 & 4) ? r11 : p11;
        float pe4 = (l7 & 4) ? p00 : r00;
        float pe5 = (l7 & 4) ? p01 : r01;
        float pe6 = (l7 & 4) ? p10 : r10;
        float pe7 = (l7 & 4) ? p11 : r11;

        ax = fmaf(pe0, x0[0], ax);  ay = fmaf(pe0, x1[0], ay);
        ax = fmaf(pe1, x0[1], ax);  ay = fmaf(pe1, x1[1], ay);
        ax = fmaf(pe2, x0[2], ax);  ay = fmaf(pe2, x1[2], ay);
        ax = fmaf(pe3, x0[3], ax);  ay = fmaf(pe3, x1[3], ay);
        ax = fmaf(pe4, x0[4], ax);  ay = fmaf(pe4, x1[4], ay);
        ax = fmaf(pe5, x0[5], ax);  ay = fmaf(pe5, x1[5], ay);
        ax = fmaf(pe6, x0[6], ax);  ay = fmaf(pe6, x1[6], ay);
        ax = fmaf(pe7, x0[7], ax);  ay = fmaf(pe7, x1[7], ay);
    }

    // total denom: ssum_l holds slot l7's sum (group-uniform); reduce 8 slots
    float st = ssum_l;
    st += __shfl_xor(st, 1, 64);
    st += __shfl_xor(st, 2, 64);
    st += __shfl_xor(st, 4, 64);
    const float inv = (st > 0.f) ? 1.f / st : 0.f;

    const float2 bv = *(const float2*)&bias[2 * lane];
    const float o0 = fmaxf(fmaf(ax, inv, bv.x), 0.f);
    const float o1 = fmaxf(fmaf(ay, inv, bv.y), 0.f);
    *(float2*)&xout[(size_t)n * DH + 2 * lane] = make_float2(o0, o1);
}

// ---------------- host launch ----------------

static inline size_t align256(size_t x) { return (x + 255) & ~(size_t)255; }

extern "C" void kernel_launch(void* const* d_in, const int* in_sizes, int n_in,
                              void* d_out, int out_size, void* d_ws, size_t ws_size,
                              hipStream_t stream) {
    (void)in_sizes; (void)n_in; (void)out_size; (void)ws_size;

    const float* x   = (const float*)d_in[0];
    const int* ei    = (const int*)d_in[1];
    const float* Wl  = (const float*)d_in[2];
    const float* bl  = (const float*)d_in[3];
    const float* Wr  = (const float*)d_in[4];
    const float* br  = (const float*)d_in[5];
    const float* att = (const float*)d_in[6];
    const float* bias= (const float*)d_in[7];
    const float* W1  = (const float*)d_in[8];
    const float* b1  = (const float*)d_in[9];
    const float* W2  = (const float*)d_in[10];
    const float* b2  = (const float*)d_in[11];
    float* out = (float*)d_out;

    const int* src = ei;
    const int* dst = ei + EE;

    const size_t EP = (size_t)EE + (size_t)NBK * 2048;  // csr capacity (incl. pad slack)

    char* w = (char*)d_ws;
    float* xA  = (float*)w; w += align256((size_t)NN * DH * 4);
    float* xB  = (float*)w; w += align256((size_t)NN * DH * 4);
    unsigned int* xl16 = (unsigned int*)w; w += align256((size_t)NN * DH * 2);
    float* xrb = (float*)w; w += align256((size_t)NN * DH * 4);
    float* hbuf = (float*)w; w += align256((size_t)NN * DH * 4);
    uint2* pairs = (uint2*)w; w += align256((size_t)EE * 8);
    int* csr_off = (int*)w; w += align256(EP * 4);
    int* prow    = (int*)w; w += align256((size_t)NN * 4);
    int* deg     = (int*)w; w += align256((size_t)NN * 4);
    int* bucket_hist   = (int*)w; w += align256(NBK * 4);
    int* bucket_base   = (int*)w; w += align256(NBK * 4);
    int* bucket_cursor = (int*)w; w += align256(NBK * 4);

    const int nb_chunk = (EE + CHUNK - 1) / CHUNK;  // 391
    const int nb_bkt  = (NN + 255) / 256;           // 196
    const int nb_gemm = (NN + 127) / 128;           // 391
    const int nb_node = (NN + 3) / 4;               // 12500

    // ---- build bucketed CSR (by dst, rows padded to 8, byte offsets) ----
    hipMemsetAsync(bucket_hist, 0, NBK * 4, stream);
    k_bhist<<<nb_chunk, 256, 0, stream>>>(dst, bucket_hist);
    k_scan_bucket<<<1, NBK, 0, stream>>>(bucket_hist, bucket_base, bucket_cursor);
    k_scatter<<<nb_chunk, 256, 0, stream>>>(src, dst, bucket_cursor, pairs);
    k_bucket<<<nb_bkt, 256, 0, stream>>>(pairs, bucket_base, bucket_hist,
                                         csr_off, prow, deg);

    // ---- 3 GATv2 layers ----
    const float* xin = x;
    for (int l = 0; l < 3; ++l) {
        const float* Wl_l = Wl + (size_t)l * DH * DH;
        const float* Wr_l = Wr + (size_t)l * DH * DH;
        const float* bl_l = bl + (size_t)l * DH;
        const float* br_l = br + (size_t)l * DH;
        const float* att_l = att + (size_t)l * DH;
        const float* bias_l = bias + (size_t)l * DH;
        float* xo = (l & 1) ? xB : xA;

        k_mfma<DH><<<dim3(nb_gemm, 2), 256, 0, stream>>>(xin, Wl_l, bl_l, xl16,
                                                         Wr_l, br_l, xrb, NN);
        k_gat_node<<<nb_node, 256, 0, stream>>>((const unsigned short*)xl16, xrb,
                                                att_l, bias_l, csr_off, prow, deg, xo);
        xin = xo;
    }

    // ---- head MLP (fp32 out; A-stage converts fp32->bf16 on the fly) ----
    k_mfma<DH><<<dim3(nb_gemm, 1), 256, 0, stream>>>(xin, W1, b1, nullptr,
                                                     nullptr, nullptr, hbuf, NN);
    k_mfma<DOUT><<<dim3(nb_gemm, 1), 256, 0, stream>>>(hbuf, W2, b2, nullptr,
                                                       nullptr, nullptr, out, NN);
}

// Round 10
// 381.388 us; speedup vs baseline: 1.8953x; 1.0805x over previous
//
#include <hip/hip_runtime.h>
#include <hip/hip_bf16.h>

#define NN 50000
#define EE 1600000
#define DH 128
#define DOUT 64
#define NEG 0.2f
#define NBK 256            // bucket array size (used: (NN+255)>>8 = 196)
#define CHUNK 4096         // edges per scatter block

typedef short bf16x8 __attribute__((ext_vector_type(8)));
typedef float f32x4 __attribute__((ext_vector_type(4)));

// ---------------- CSR build (bucketed, no per-edge global atomics) ----------------

__global__ __launch_bounds__(256) void k_bhist(const int* __restrict__ dst,
                                               int* __restrict__ bucket_hist) {
    __shared__ int lh[NBK];
    lh[threadIdx.x] = 0;
    __syncthreads();
    const int e0 = blockIdx.x * CHUNK;
    #pragma unroll
    for (int k = 0; k < CHUNK / 256; k++) {
        int e = e0 + k * 256 + threadIdx.x;
        if (e < EE) atomicAdd(&lh[((unsigned)dst[e]) >> 8], 1);
    }
    __syncthreads();
    int c = lh[threadIdx.x];
    if (c) atomicAdd(&bucket_hist[threadIdx.x], c);
}

__global__ __launch_bounds__(256) void k_scan_bucket(const int* __restrict__ bucket_hist,
                                                     int* __restrict__ bucket_base,
                                                     int* __restrict__ bucket_cursor) {
    __shared__ int tmp[NBK];
    int t = threadIdx.x;
    int v = bucket_hist[t];
    tmp[t] = v;
    __syncthreads();
    #pragma unroll
    for (int off = 1; off < NBK; off <<= 1) {
        int tt = (t >= off) ? tmp[t - off] : 0;
        __syncthreads();
        tmp[t] += tt;
        __syncthreads();
    }
    bucket_base[t] = tmp[t] - v;
    bucket_cursor[t] = tmp[t] - v;
}

// scatter packed (dstlow<<16 | src) into bucket-contiguous regions
__global__ __launch_bounds__(256) void k_scatter(const int* __restrict__ src,
                                                 const int* __restrict__ dst,
                                                 int* __restrict__ bucket_cursor,
                                                 unsigned int* __restrict__ pairs) {
    __shared__ int lh[NBK];
    __shared__ int lbase[NBK];
    lh[threadIdx.x] = 0;
    __syncthreads();
    const int e0 = blockIdx.x * CHUNK;
    int dl[CHUNK / 256];
    #pragma unroll
    for (int k = 0; k < CHUNK / 256; k++) {
        int e = e0 + k * 256 + threadIdx.x;
        dl[k] = (e < EE) ? dst[e] : -1;
        if (dl[k] >= 0) atomicAdd(&lh[((unsigned)dl[k]) >> 8], 1);
    }
    __syncthreads();
    int c = lh[threadIdx.x];
    lbase[threadIdx.x] = c ? atomicAdd(&bucket_cursor[threadIdx.x], c) : 0;
    __syncthreads();
    lh[threadIdx.x] = 0;   // reuse as local running cursor
    __syncthreads();
    #pragma unroll
    for (int k = 0; k < CHUNK / 256; k++) {
        int e = e0 + k * 256 + threadIdx.x;
        if (dl[k] >= 0) {
            int b = ((unsigned)dl[k]) >> 8;
            int loc = atomicAdd(&lh[b], 1);
            pairs[lbase[b] + loc] =
                (unsigned)src[e] | (((unsigned)dl[k] & 255u) << 16);
        }
    }
}

// per-bucket: LDS histogram + padded scan + fill + pad; writes deg/prow/csr.
__global__ __launch_bounds__(256) void k_bucket(const unsigned int* __restrict__ pairs,
                                                const int* __restrict__ bucket_base,
                                                const int* __restrict__ bucket_hist,
                                                int* __restrict__ csr_off,
                                                int* __restrict__ prow,
                                                int* __restrict__ deg) {
    __shared__ int cnt[256];
    __shared__ int sbase[256];
    __shared__ int scn[256];
    __shared__ int cur[256];
    const int b = blockIdx.x;
    const int t = threadIdx.x;
    const int pstart = bucket_base[b];
    const int pcnt = bucket_hist[b];

    cnt[t] = 0;
    cur[t] = 0;
    __syncthreads();
    for (int i = t; i < pcnt; i += 256)
        atomicAdd(&cnt[pairs[pstart + i] >> 16], 1);
    __syncthreads();

    const int d = cnt[t];
    const int padded = (d + 7) & ~7;
    scn[t] = padded;
    __syncthreads();
    #pragma unroll
    for (int off = 1; off < 256; off <<= 1) {
        int v = (t >= off) ? scn[t - off] : 0;
        __syncthreads();
        scn[t] += v;
        __syncthreads();
    }
    const int mybase = scn[t] - padded;   // exclusive scan (bucket-relative)
    sbase[t] = mybase;
    const int cb = pstart + b * 2048;     // csr region base for this bucket
    const int node = b * 256 + t;
    if (node < NN) {
        prow[node] = cb + mybase;
        deg[node] = d;
    }
    __syncthreads();

    for (int i = t; i < pcnt; i += 256) {
        unsigned int pr = pairs[pstart + i];
        int ln = (int)(pr >> 16);
        int pos = atomicAdd(&cur[ln], 1);
        csr_off[cb + sbase[ln] + pos] = (int)((pr & 0xffffu) << 8);
    }
    __syncthreads();

    for (int p = d; p < padded; p++) csr_off[cb + mybase + p] = 0;
}

// ---------------- helpers ----------------

static __device__ __forceinline__ unsigned int f2bf(float f) {
    unsigned int u = __float_as_uint(f);
    return (u + 0x7fffu + ((u >> 16) & 1u)) >> 16;  // RNE
}
static __device__ __forceinline__ unsigned int pack2bf(float lo, float hi) {
    return f2bf(lo) | (f2bf(hi) << 16);
}

// ---------------- MFMA GEMM: C[n,m] = sum_k X[n,k]*W[m,k] + b[m] ----------------
// K = 128. A = X rows: fp32 (ABF=false, converted on stage) or packed bf16
// (ABF=true, straight uint4 copy). B = W rows (fp32 -> bf16). LDS layout
// [kc][kg][row][8]: ds_read_b128 fragments contiguous per 16-lane group.
// blockIdx.y==0: bf16-packed out to C0bf (W0,b0); y==1: fp32 out C1 (W1,b1).

template <bool ABF>
__global__ __launch_bounds__(256) void k_mfma(const void* __restrict__ X,
                                              const float* __restrict__ W0,
                                              const float* __restrict__ b0,
                                              unsigned int* __restrict__ C0bf,
                                              const float* __restrict__ W1,
                                              const float* __restrict__ b1,
                                              float* __restrict__ C1,
                                              int nrows) {
    constexpr int BN = 128;
    constexpr int MF = 4, NF = 4;
    __shared__ __align__(16) unsigned short As[4][4][128][8];
    __shared__ __align__(16) unsigned short Bs[4][4][BN][8];

    const int tid = threadIdx.x;
    const int row0 = blockIdx.x * 128;
    const bool bfout = (blockIdx.y == 0);
    const float* W = bfout ? W0 : W1;
    const float* bias = bfout ? b0 : b1;

    // stage A
    if constexpr (ABF) {
        const uint4* X4 = (const uint4*)X;
        #pragma unroll
        for (int i = 0; i < 8; i++) {
            int L = i * 256 + tid;          // 2048 uint4 (128 rows x 16)
            int r = L >> 4, q = L & 15;
            int gr = row0 + r;
            uint4 v = make_uint4(0u, 0u, 0u, 0u);
            if (gr < nrows) v = X4[(size_t)gr * 16 + q];
            *(uint4*)&As[q >> 2][q & 3][r][0] = v;
        }
    } else {
        const float* Xf = (const float*)X;
        #pragma unroll
        for (int i = 0; i < 16; i++) {
            int L = i * 256 + tid;          // 4096 float4
            int r = L >> 5, kq = L & 31;
            int gr = row0 + r;
            float4 v = make_float4(0.f, 0.f, 0.f, 0.f);
            if (gr < nrows) v = *(const float4*)&Xf[(size_t)gr * 128 + kq * 4];
            int k = kq * 4;
            *(uint2*)&As[k >> 5][(k >> 3) & 3][r][k & 7] =
                make_uint2(pack2bf(v.x, v.y), pack2bf(v.z, v.w));
        }
    }
    // stage B: BN rows x 128 cols fp32 -> bf16
    #pragma unroll
    for (int i = 0; i < (BN * 32) / 256; i++) {
        int L = i * 256 + tid;
        int r = L >> 5, kq = L & 31;
        float4 v = *(const float4*)&W[(size_t)r * 128 + kq * 4];
        int k = kq * 4;
        *(uint2*)&Bs[k >> 5][(k >> 3) & 3][r][k & 7] =
            make_uint2(pack2bf(v.x, v.y), pack2bf(v.z, v.w));
    }
    __syncthreads();

    const int w = tid >> 6;
    const int lane = tid & 63;
    const int lr = lane & 15;
    const int kg = lane >> 4;
    const int rowbase = (w >> 1) * 64;
    const int colbase = (w & 1) * 64;

    f32x4 acc[MF][NF];
    #pragma unroll
    for (int i = 0; i < MF; i++)
        #pragma unroll
        for (int j = 0; j < NF; j++) acc[i][j] = (f32x4){0.f, 0.f, 0.f, 0.f};

    #pragma unroll
    for (int kc = 0; kc < 4; kc++) {
        bf16x8 af[MF], bfr[NF];
        #pragma unroll
        for (int i = 0; i < MF; i++)
            af[i] = *(const bf16x8*)&As[kc][kg][rowbase + i * 16 + lr][0];
        #pragma unroll
        for (int j = 0; j < NF; j++)
            bfr[j] = *(const bf16x8*)&Bs[kc][kg][colbase + j * 16 + lr][0];
        #pragma unroll
        for (int i = 0; i < MF; i++)
            #pragma unroll
            for (int j = 0; j < NF; j++)
                acc[i][j] = __builtin_amdgcn_mfma_f32_16x16x32_bf16(af[i], bfr[j],
                                                                    acc[i][j], 0, 0, 0);
    }

    // epilogue: C/D layout col = lane&15, row = (lane>>4)*4 + reg
    #pragma unroll
    for (int i = 0; i < MF; i++) {
        #pragma unroll
        for (int reg = 0; reg < 4; reg++) {
            int row = rowbase + i * 16 + (lane >> 4) * 4 + reg;
            int gr = row0 + row;
            if (gr < nrows) {
                #pragma unroll
                for (int j = 0; j < NF; j++) {
                    int col = colbase + j * 16 + lr;
                    float v = acc[i][j][reg] + bias[col];
                    if (bfout) {
                        float vn = __shfl_xor(v, 1, 64);
                        if (!(lane & 1)) {
                            C0bf[(size_t)gr * (BN / 2) + (col >> 1)] = pack2bf(v, vn);
                        }
                    } else {
                        C1[(size_t)gr * BN + col] = v;
                    }
                }
            }
        }
    }
}

// ---------------- fused head: out = (X@W1.T + b1)@W2.T + b2 ----------------
// X is packed bf16 (NN x 128). Phase 1: h tile (128x128) via MFMA, +b1,
// packed bf16 back into As (LDS reuse). Phase 2: h @ W2.T (64 out cols).

__global__ __launch_bounds__(256) void k_head(const void* __restrict__ Xbf,
                                              const float* __restrict__ W1,
                                              const float* __restrict__ b1,
                                              const float* __restrict__ W2,
                                              const float* __restrict__ b2,
                                              float* __restrict__ out,
                                              int nrows) {
    __shared__ __align__(16) unsigned short As[4][4][128][8];
    __shared__ __align__(16) unsigned short Bs[4][4][128][8];

    const int tid = threadIdx.x;
    const int row0 = blockIdx.x * 128;

    // stage A (bf16 copy)
    const uint4* X4 = (const uint4*)Xbf;
    #pragma unroll
    for (int i = 0; i < 8; i++) {
        int L = i * 256 + tid;
        int r = L >> 4, q = L & 15;
        int gr = row0 + r;
        uint4 v = make_uint4(0u, 0u, 0u, 0u);
        if (gr < nrows) v = X4[(size_t)gr * 16 + q];
        *(uint4*)&As[q >> 2][q & 3][r][0] = v;
    }
    // stage W1 (128x128 fp32 -> bf16)
    #pragma unroll
    for (int i = 0; i < 16; i++) {
        int L = i * 256 + tid;
        int r = L >> 5, kq = L & 31;
        float4 v = *(const float4*)&W1[(size_t)r * 128 + kq * 4];
        int k = kq * 4;
        *(uint2*)&Bs[k >> 5][(k >> 3) & 3][r][k & 7] =
            make_uint2(pack2bf(v.x, v.y), pack2bf(v.z, v.w));
    }
    __syncthreads();

    const int w = tid >> 6;
    const int lane = tid & 63;
    const int lr = lane & 15;
    const int kg = lane >> 4;
    const int rowbase = (w >> 1) * 64;
    const int colbase = (w & 1) * 64;

    f32x4 acc[4][4];
    #pragma unroll
    for (int i = 0; i < 4; i++)
        #pragma unroll
        for (int j = 0; j < 4; j++) acc[i][j] = (f32x4){0.f, 0.f, 0.f, 0.f};

    #pragma unroll
    for (int kc = 0; kc < 4; kc++) {
        bf16x8 af[4], bfr[4];
        #pragma unroll
        for (int i = 0; i < 4; i++)
            af[i] = *(const bf16x8*)&As[kc][kg][rowbase + i * 16 + lr][0];
        #pragma unroll
        for (int j = 0; j < 4; j++)
            bfr[j] = *(const bf16x8*)&Bs[kc][kg][colbase + j * 16 + lr][0];
        #pragma unroll
        for (int i = 0; i < 4; i++)
            #pragma unroll
            for (int j = 0; j < 4; j++)
                acc[i][j] = __builtin_amdgcn_mfma_f32_16x16x32_bf16(af[i], bfr[j],
                                                                    acc[i][j], 0, 0, 0);
    }
    __syncthreads();   // all waves done reading As/Bs

    // write h (+b1, bf16) back into As; restage Bs rows 0..63 with W2
    #pragma unroll
    for (int i = 0; i < 4; i++) {
        #pragma unroll
        for (int reg = 0; reg < 4; reg++) {
            int row = rowbase + i * 16 + (lane >> 4) * 4 + reg;
            #pragma unroll
            for (int j = 0; j < 4; j++) {
                int col = colbase + j * 16 + lr;
                float v = acc[i][j][reg] + b1[col];
                float vn = __shfl_xor(v, 1, 64);
                if (!(lane & 1)) {
                    *(unsigned int*)&As[col >> 5][(col >> 3) & 3][row][col & 7] =
                        pack2bf(v, vn);
                }
            }
        }
    }
    #pragma unroll
    for (int i = 0; i < 8; i++) {
        int L = i * 256 + tid;          // 64 rows x 32 float4
        int r = L >> 5, kq = L & 31;
        float4 v = *(const float4*)&W2[(size_t)r * 128 + kq * 4];
        int k = kq * 4;
        *(uint2*)&Bs[k >> 5][(k >> 3) & 3][r][k & 7] =
            make_uint2(pack2bf(v.x, v.y), pack2bf(v.z, v.w));
    }
    __syncthreads();

    // phase 2: rows w*32..w*32+31, cols 0..63
    const int rowbase2 = w * 32;
    f32x4 acc2[2][4];
    #pragma unroll
    for (int i = 0; i < 2; i++)
        #pragma unroll
        for (int j = 0; j < 4; j++) acc2[i][j] = (f32x4){0.f, 0.f, 0.f, 0.f};

    #pragma unroll
    for (int kc = 0; kc < 4; kc++) {
        bf16x8 af2[2], bf2[4];
        #pragma unroll
        for (int i = 0; i < 2; i++)
            af2[i] = *(const bf16x8*)&As[kc][kg][rowbase2 + i * 16 + lr][0];
        #pragma unroll
        for (int j = 0; j < 4; j++)
            bf2[j] = *(const bf16x8*)&Bs[kc][kg][j * 16 + lr][0];
        #pragma unroll
        for (int i = 0; i < 2; i++)
            #pragma unroll
            for (int j = 0; j < 4; j++)
                acc2[i][j] = __builtin_amdgcn_mfma_f32_16x16x32_bf16(af2[i], bf2[j],
                                                                     acc2[i][j], 0, 0, 0);
    }

    #pragma unroll
    for (int i = 0; i < 2; i++) {
        #pragma unroll
        for (int reg = 0; reg < 4; reg++) {
            int row = rowbase2 + i * 16 + (lane >> 4) * 4 + reg;
            int gr = row0 + row;
            if (gr < nrows) {
                #pragma unroll
                for (int j = 0; j < 4; j++) {
                    int col = j * 16 + lr;
                    out[(size_t)gr * DOUT + col] = acc2[i][j][reg] + b2[col];
                }
            }
        }
    }
}

// ---------------- fused per-node softmax + aggregate ----------------
// one wave per node; lane owns dims (2*lane, 2*lane+1). 8-edge batches;
// merge tree + butterfly for logits, unmerge tree for pe broadcast.
// Output written as packed bf16 (identical RNE rounding the GEMM A-stage
// would apply anyway).

__global__ __launch_bounds__(256) void k_gat_node(const unsigned short* __restrict__ xl16,
                                                  const float* __restrict__ xr,
                                                  const float* __restrict__ att,
                                                  const float* __restrict__ bias,
                                                  const int* __restrict__ csr_off,
                                                  const int* __restrict__ prow,
                                                  const int* __restrict__ deg,
                                                  unsigned int* __restrict__ xout) {
    const int lane = threadIdx.x & 63;
    const int n = blockIdx.x * 4 + (threadIdx.x >> 6);
    if (n >= NN) return;

    const int l7 = lane & 7;
    const float2 xrv = *(const float2*)&xr[(size_t)n * DH + 2 * lane];
    const float2 attv = *(const float2*)&att[2 * lane];
    const int p0 = prow[n];
    const int dg = deg[n];
    const int pend = p0 + dg;
    const int pend_pad = p0 + ((dg + 7) & ~7);

    float ssum_l = 0.f;
    float ax = 0.f, ay = 0.f;

    const char* xlb = (const char*)xl16;
    const unsigned int lb = (unsigned int)lane * 4u;

    for (int p = p0; p < pend_pad; p += 8) {
        uint4 ia = *(const uint4*)&csr_off[p];
        uint4 ib = *(const uint4*)&csr_off[p + 4];
        unsigned int u0 = *(const unsigned int*)(xlb + (ia.x + lb));
        unsigned int u1 = *(const unsigned int*)(xlb + (ia.y + lb));
        unsigned int u2 = *(const unsigned int*)(xlb + (ia.z + lb));
        unsigned int u3 = *(const unsigned int*)(xlb + (ia.w + lb));
        unsigned int u4 = *(const unsigned int*)(xlb + (ib.x + lb));
        unsigned int u5 = *(const unsigned int*)(xlb + (ib.y + lb));
        unsigned int u6 = *(const unsigned int*)(xlb + (ib.z + lb));
        unsigned int u7 = *(const unsigned int*)(xlb + (ib.w + lb));
        unsigned int uu[8] = {u0, u1, u2, u3, u4, u5, u6, u7};

        float x0[8], x1[8], w[8];
        #pragma unroll
        for (int j = 0; j < 8; j++) {
            x0[j] = __uint_as_float(uu[j] << 16);
            x1[j] = __uint_as_float(uu[j] & 0xffff0000u);
            float z0 = x0[j] + xrv.x;
            float z1 = x1[j] + xrv.y;
            float l0 = fmaxf(z0, NEG * z0);
            float l1 = fmaxf(z1, NEG * z1);
            w[j] = fmaf(l0, attv.x, l1 * attv.y);
        }

        // merge tree
        float v4[4], v2[2], S;
        {
            const bool hi = (lane & 1);
            #pragma unroll
            for (int i = 0; i < 4; i++) {
                float keep = hi ? w[2 * i + 1] : w[2 * i];
                float send = hi ? w[2 * i] : w[2 * i + 1];
                v4[i] = keep + __shfl_xor(send, 1, 64);
            }
        }
        {
            const bool hi = (lane & 2);
            #pragma unroll
            for (int i = 0; i < 2; i++) {
                float keep = hi ? v4[2 * i + 1] : v4[2 * i];
                float send = hi ? v4[2 * i] : v4[2 * i + 1];
                v2[i] = keep + __shfl_xor(send, 2, 64);
            }
        }
        {
            const bool hi = (lane & 4);
            float keep = hi ? v2[1] : v2[0];
            float send = hi ? v2[0] : v2[1];
            S = keep + __shfl_xor(send, 4, 64);
        }
        S += __shfl_xor(S, 8, 64);
        S += __shfl_xor(S, 16, 64);
        S += __shfl_xor(S, 32, 64);

        float pe = (p + l7 < pend) ? __expf(S) : 0.f;
        ssum_l += pe;

        // unmerge tree: pe -> pe[0..7] on every lane
        float q = __shfl_xor(pe, 1, 64);
        float pA = (l7 & 1) ? q : pe;
        float pB = (l7 & 1) ? pe : q;
        float qA = __shfl_xor(pA, 2, 64);
        float qB = __shfl_xor(pB, 2, 64);
        float p00 = (l7 & 2) ? qA : pA;
        float p01 = (l7 & 2) ? qB : pB;
        float p10 = (l7 & 2) ? pA : qA;
        float p11 = (l7 & 2) ? pB : qB;
        float r00 = __shfl_xor(p00, 4, 64);
        float r01 = __shfl_xor(p01, 4, 64);
        float r10 = __shfl_xor(p10, 4, 64);
        float r11 = __shfl_xor(p11, 4, 64);
        float pe0 = (l7 & 4) ? r00 : p00;
        float pe1 = (l7 & 4) ? r01 : p01;
        float pe2 = (l7 & 4) ? r10 : p10;
        float pe3 = (l7 & 4) ? r11 : p11;
        float pe4 = (l7 & 4) ? p00 : r00;
        float pe5 = (l7 & 4) ? p01 : r01;
        float pe6 = (l7 & 4) ? p10 : r10;
        float pe7 = (l7 & 4) ? p11 : r11;

        ax = fmaf(pe0, x0[0], ax);  ay = fmaf(pe0, x1[0], ay);
        ax = fmaf(pe1, x0[1], ax);  ay = fmaf(pe1, x1[1], ay);
        ax = fmaf(pe2, x0[2], ax);  ay = fmaf(pe2, x1[2], ay);
        ax = fmaf(pe3, x0[3], ax);  ay = fmaf(pe3, x1[3], ay);
        ax = fmaf(pe4, x0[4], ax);  ay = fmaf(pe4, x1[4], ay);
        ax = fmaf(pe5, x0[5], ax);  ay = fmaf(pe5, x1[5], ay);
        ax = fmaf(pe6, x0[6], ax);  ay = fmaf(pe6, x1[6], ay);
        ax = fmaf(pe7, x0[7], ax);  ay = fmaf(pe7, x1[7], ay);
    }

    float st = ssum_l;
    st += __shfl_xor(st, 1, 64);
    st += __shfl_xor(st, 2, 64);
    st += __shfl_xor(st, 4, 64);
    const float inv = (st > 0.f) ? 1.f / st : 0.f;

    const float2 bv = *(const float2*)&bias[2 * lane];
    const float o0 = fmaxf(fmaf(ax, inv, bv.x), 0.f);
    const float o1 = fmaxf(fmaf(ay, inv, bv.y), 0.f);
    xout[(size_t)n * (DH / 2) + lane] = pack2bf(o0, o1);
}

// ---------------- host launch ----------------

static inline size_t align256(size_t x) { return (x + 255) & ~(size_t)255; }

extern "C" void kernel_launch(void* const* d_in, const int* in_sizes, int n_in,
                              void* d_out, int out_size, void* d_ws, size_t ws_size,
                              hipStream_t stream) {
    (void)in_sizes; (void)n_in; (void)out_size; (void)ws_size;

    const float* x   = (const float*)d_in[0];
    const int* ei    = (const int*)d_in[1];
    const float* Wl  = (const float*)d_in[2];
    const float* bl  = (const float*)d_in[3];
    const float* Wr  = (const float*)d_in[4];
    const float* br  = (const float*)d_in[5];
    const float* att = (const float*)d_in[6];
    const float* bias= (const float*)d_in[7];
    const float* W1  = (const float*)d_in[8];
    const float* b1  = (const float*)d_in[9];
    const float* W2  = (const float*)d_in[10];
    const float* b2  = (const float*)d_in[11];
    float* out = (float*)d_out;

    const int* src = ei;
    const int* dst = ei + EE;

    const size_t EP = (size_t)EE + (size_t)NBK * 2048;  // csr capacity incl. slack

    char* w = (char*)d_ws;
    unsigned int* xA = (unsigned int*)w; w += align256((size_t)NN * (DH / 2) * 4);
    unsigned int* xB = (unsigned int*)w; w += align256((size_t)NN * (DH / 2) * 4);
    unsigned int* xl16 = (unsigned int*)w; w += align256((size_t)NN * DH * 2);
    float* xrb = (float*)w; w += align256((size_t)NN * DH * 4);
    unsigned int* pairs = (unsigned int*)w; w += align256((size_t)EE * 4);
    int* csr_off = (int*)w; w += align256(EP * 4);
    int* prow    = (int*)w; w += align256((size_t)NN * 4);
    int* deg     = (int*)w; w += align256((size_t)NN * 4);
    int* bucket_hist   = (int*)w; w += align256(NBK * 4);
    int* bucket_base   = (int*)w; w += align256(NBK * 4);
    int* bucket_cursor = (int*)w; w += align256(NBK * 4);

    const int nb_chunk = (EE + CHUNK - 1) / CHUNK;  // 391
    const int nb_bkt  = (NN + 255) / 256;           // 196
    const int nb_gemm = (NN + 127) / 128;           // 391
    const int nb_node = (NN + 3) / 4;               // 12500

    // ---- build bucketed CSR (by dst, rows padded to 8, byte offsets) ----
    hipMemsetAsync(bucket_hist, 0, NBK * 4, stream);
    k_bhist<<<nb_chunk, 256, 0, stream>>>(dst, bucket_hist);
    k_scan_bucket<<<1, NBK, 0, stream>>>(bucket_hist, bucket_base, bucket_cursor);
    k_scatter<<<nb_chunk, 256, 0, stream>>>(src, dst, bucket_cursor, pairs);
    k_bucket<<<nb_bkt, 256, 0, stream>>>(pairs, bucket_base, bucket_hist,
                                         csr_off, prow, deg);

    // ---- 3 GATv2 layers ----
    const void* xin = (const void*)x;   // layer 0: fp32
    for (int l = 0; l < 3; ++l) {
        const float* Wl_l = Wl + (size_t)l * DH * DH;
        const float* Wr_l = Wr + (size_t)l * DH * DH;
        const float* bl_l = bl + (size_t)l * DH;
        const float* br_l = br + (size_t)l * DH;
        const float* att_l = att + (size_t)l * DH;
        const float* bias_l = bias + (size_t)l * DH;
        unsigned int* xo = (l & 1) ? xB : xA;

        if (l == 0)
            k_mfma<false><<<dim3(nb_gemm, 2), 256, 0, stream>>>(xin, Wl_l, bl_l, xl16,
                                                                Wr_l, br_l, xrb, NN);
        else
            k_mfma<true><<<dim3(nb_gemm, 2), 256, 0, stream>>>(xin, Wl_l, bl_l, xl16,
                                                               Wr_l, br_l, xrb, NN);
        k_gat_node<<<nb_node, 256, 0, stream>>>((const unsigned short*)xl16, xrb,
                                                att_l, bias_l, csr_off, prow, deg, xo);
        xin = (const void*)xo;
    }

    // ---- fused head MLP ----
    k_head<<<nb_gemm, 256, 0, stream>>>(xin, W1, b1, W2, b2, out, NN);
}